// Round 6
// baseline (387.449 us; speedup 1.0000x reference)
//
#include <hip/hip_runtime.h>
#include <cstdint>

typedef unsigned short u16;
typedef __attribute__((ext_vector_type(4))) unsigned short u16x4;
typedef __attribute__((ext_vector_type(8))) short short8;
typedef __attribute__((ext_vector_type(4))) float f32x4;

#define DI 512
#define CIN 1024
#define NPIX 4096   // 64*64
#define MPIX 1024   // 32*32

__device__ __forceinline__ float bf2f(u16 u) {
  union { unsigned int i; float f; } v; v.i = ((unsigned int)u) << 16; return v.f;
}
__device__ __forceinline__ u16 f2bf(float f) {
  union { float f; unsigned int i; } v; v.f = f;
  unsigned int r = v.i + 0x7fffu + ((v.i >> 16) & 1u);
  return (u16)(r >> 16);
}
__device__ __forceinline__ void unpack8(uint4 v, float* f) {
  union { unsigned int i; float f; } u;
  u.i = v.x << 16;          f[0] = u.f;
  u.i = v.x & 0xffff0000u;  f[1] = u.f;
  u.i = v.y << 16;          f[2] = u.f;
  u.i = v.y & 0xffff0000u;  f[3] = u.f;
  u.i = v.z << 16;          f[4] = u.f;
  u.i = v.z & 0xffff0000u;  f[5] = u.f;
  u.i = v.w << 16;          f[6] = u.f;
  u.i = v.w & 0xffff0000u;  f[7] = u.f;
}

// async global->LDS, 16B per lane, wave-uniform LDS base + lane*16
__device__ __forceinline__ void gload16(const u16* g, u16* l) {
  __builtin_amdgcn_global_load_lds(
      (const __attribute__((address_space(1))) void*)g,
      (__attribute__((address_space(3))) void*)l, 16, 0, 0);
}

// ---------------- f32 -> bf16 convert (4 weight tensors in one launch) ----
__global__ __launch_bounds__(256) void cvt4_kernel(
    const float* __restrict__ s0, const float* __restrict__ s1,
    const float* __restrict__ s2, const float* __restrict__ s3,
    u16* __restrict__ d0, u16* __restrict__ d1,
    u16* __restrict__ d2, u16* __restrict__ d3) {
  int i = blockIdx.x * 256 + threadIdx.x;     // 0 .. 4*131072
  int sel = i >> 17;
  int j = i & 131071;
  const float* src = sel == 0 ? s0 : sel == 1 ? s1 : sel == 2 ? s2 : s3;
  u16* dst = sel == 0 ? d0 : sel == 1 ? d1 : sel == 2 ? d2 : d3;
  float4 v = *(const float4*)(src + (long)j * 4);
  u16x4 w;
  w[0] = f2bf(v.x); w[1] = f2bf(v.y); w[2] = f2bf(v.z); w[3] = f2bf(v.w);
  *(u16x4*)(dst + (long)j * 4) = w;
}

// ------- x [b][c][n] f32 -> x_T [b][n][c] bf16 + fused 2x2 maxpool -------
// Block covers 128 n (= 2 image rows) x 64 c. Pool outputs 32 m x 64 c.
__global__ __launch_bounds__(256) void transpose_pool_kernel(
    const float* __restrict__ x, u16* __restrict__ xT, u16* __restrict__ poolT) {
  __shared__ u16 tile[64][136];
  const int b = blockIdx.z;
  const int n0 = blockIdx.x * 128, c0 = blockIdx.y * 64;
  const float* xb = x + (long)b * CIN * NPIX;
  u16* xTb = xT + (long)b * NPIX * CIN;
  const int t = threadIdx.x;
  const int tc = t >> 5, tn = (t & 31) * 4;
  #pragma unroll
  for (int i = 0; i < 8; i++) {
    int c = tc + i * 8;
    float4 v = *(const float4*)(xb + (long)(c0 + c) * NPIX + n0 + tn);
    tile[c][tn + 0] = f2bf(v.x);
    tile[c][tn + 1] = f2bf(v.y);
    tile[c][tn + 2] = f2bf(v.z);
    tile[c][tn + 3] = f2bf(v.w);
  }
  __syncthreads();
  // write xT
  const int tn2 = t >> 4, tc2 = (t & 15) * 4;
  #pragma unroll
  for (int i = 0; i < 8; i++) {
    int n = tn2 + i * 16;
    u16x4 w;
    w[0] = tile[tc2 + 0][n];
    w[1] = tile[tc2 + 1][n];
    w[2] = tile[tc2 + 2][n];
    w[3] = tile[tc2 + 3][n];
    *(u16x4*)(xTb + (long)(n0 + n) * CIN + c0 + tc2) = w;
  }
  // fused pool: output row m = blockIdx.x*32 + j
  const int j = t >> 3, c8 = (t & 7) * 8;
  u16 r[8] __attribute__((aligned(16)));
  #pragma unroll
  for (int k = 0; k < 8; k++) {
    int c = c8 + k;
    float m0 = fmaxf(bf2f(tile[c][2 * j]), bf2f(tile[c][2 * j + 1]));
    float m1 = fmaxf(bf2f(tile[c][64 + 2 * j]), bf2f(tile[c][64 + 2 * j + 1]));
    r[k] = f2bf(fmaxf(m0, m1));
  }
  *(uint4*)(poolT + ((long)b * MPIX + blockIdx.x * 32 + j) * CIN + c0 + c8) =
      *(uint4*)r;
}

// ---------------- GEMM: C[M][N] = A[M][K] * B[N][K]^T ----
// global_load_lds staging, linear LDS [128][64] bf16, XOR-swizzled 16B slots.
// OM: 0 = bf16 plain, 1 = bf16 transposed [N][M], 2 = f32 plain.
// HAS_EXP: v = exp(acc*scale); writes per-block row-sums to
//          psum_out[(z*gridX + x)*4096 + row].
// HAS_PSUM2: writes per-block row (sum, sumsq) to
//          psum_out[blk*256 + {row, 128+row}], blk = (z*gridY+y)*gridX+x.
template<int OM, bool HAS_BIAS, bool HAS_CS, bool HAS_SHIFT, bool HAS_EXP, bool HAS_PSUM2>
__global__ __launch_bounds__(256)
void gemm_tn(const u16* __restrict__ A, const u16* __restrict__ B,
             void* __restrict__ Cv,
             const float* __restrict__ bias, long sBias,
             const float* __restrict__ cs, long sCS,
             const float* __restrict__ shift, long sShift,
             float* __restrict__ psum_out,
             float scale, int M, int N, int K, long sA, long sB, long sC)
{
  A += blockIdx.z * sA;
  B += blockIdx.z * sB;
  if (HAS_BIAS) bias += blockIdx.z * sBias;
  if (HAS_CS) cs += blockIdx.z * sCS;
  if (HAS_SHIFT) shift += blockIdx.z * sShift;
  const int bm = blockIdx.y * 128;
  const int bn = blockIdx.x * 128;
  __shared__ __align__(16) u16 As[128 * 64];
  __shared__ __align__(16) u16 Bs[128 * 64];
  __shared__ float psum[4][128];
  const int tid = threadIdx.x;
  const int lane = tid & 63;
  const int wave = tid >> 6;
  const int wm = (wave >> 1) * 64;
  const int wn = (wave & 1) * 64;
  const int lr = lane & 15;          // frag row (A) / col (B,D)
  const int q  = lane >> 4;          // 16B slot quarter within k
  const int sxor = lane & 7;
  f32x4 acc[4][4] = {};

  const int swz = ((lane & 7) ^ (lane >> 3)) * 8;
  const long grow = 32 * wave + (lane >> 3);
  const u16* Ag = A + ((long)bm + grow) * K + swz;
  const u16* Bg = B + ((long)bn + grow) * K + swz;

  for (int kt = 0; kt < K; kt += 64) {
    __syncthreads();
    #pragma unroll
    for (int i = 0; i < 4; i++) {
      gload16(Ag + (long)(8 * i) * K + kt, &As[(wave * 4 + i) * 512]);
      gload16(Bg + (long)(8 * i) * K + kt, &Bs[(wave * 4 + i) * 512]);
    }
    __syncthreads();
    #pragma unroll
    for (int kk = 0; kk < 2; kk++) {
      short8 av[4], bv[4];
      #pragma unroll
      for (int mi = 0; mi < 4; mi++)
        av[mi] = *(const short8*)&As[(wm + mi * 16 + lr) * 64 +
                                     (((kk << 2) + q) ^ sxor) * 8];
      #pragma unroll
      for (int ni = 0; ni < 4; ni++)
        bv[ni] = *(const short8*)&Bs[(wn + ni * 16 + lr) * 64 +
                                     (((kk << 2) + q) ^ sxor) * 8];
      #pragma unroll
      for (int mi = 0; mi < 4; mi++) {
        #pragma unroll
        for (int ni = 0; ni < 4; ni++)
          acc[mi][ni] = __builtin_amdgcn_mfma_f32_16x16x32_bf16(
              av[mi], bv[ni], acc[mi][ni], 0, 0, 0);
      }
    }
  }

  const int dr = (lane >> 4) * 4;
  float rowsum[4][4];
  float rowsq[4][4];
  if (HAS_EXP || HAS_PSUM2) {
    #pragma unroll
    for (int mi = 0; mi < 4; mi++)
      #pragma unroll
      for (int r = 0; r < 4; r++) { rowsum[mi][r] = 0.f; rowsq[mi][r] = 0.f; }
  }
  #pragma unroll
  for (int mi = 0; mi < 4; mi++) {
    const int rowb = bm + wm + mi * 16 + dr;
    float bvs[4] = {0.f, 0.f, 0.f, 0.f};
    float shv[4] = {0.f, 0.f, 0.f, 0.f};
    if (HAS_BIAS) {
      #pragma unroll
      for (int r = 0; r < 4; r++) bvs[r] = bias[rowb + r];
    }
    if (HAS_SHIFT) {
      #pragma unroll
      for (int r = 0; r < 4; r++) shv[r] = shift[rowb + r];
    }
    #pragma unroll
    for (int ni = 0; ni < 4; ni++) {
      const int col = bn + wn + ni * 16 + lr;
      const float csv = HAS_CS ? cs[col] : 1.0f;
      float v[4];
      #pragma unroll
      for (int r = 0; r < 4; r++) {
        float t = acc[mi][ni][r] * scale;
        if (HAS_CS) t *= csv;
        if (HAS_SHIFT) t -= shv[r];
        if (HAS_BIAS) t += bvs[r];
        if (HAS_EXP) t = expf(t);
        if (HAS_EXP || HAS_PSUM2) rowsum[mi][r] += t;
        if (HAS_PSUM2) rowsq[mi][r] += t * t;
        v[r] = t;
      }
      if (OM == 1) {
        u16* C = (u16*)Cv + blockIdx.z * sC;
        u16x4 w;
        #pragma unroll
        for (int r = 0; r < 4; r++) w[r] = f2bf(v[r]);
        *(u16x4*)(C + (long)col * M + rowb) = w;
      } else if (OM == 0) {
        u16* C = (u16*)Cv + blockIdx.z * sC;
        #pragma unroll
        for (int r = 0; r < 4; r++)
          C[(long)(rowb + r) * N + col] = f2bf(v[r]);
      } else {
        float* C = (float*)Cv + blockIdx.z * sC;
        #pragma unroll
        for (int r = 0; r < 4; r++)
          C[(long)(rowb + r) * N + col] = v[r];
      }
    }
  }
  if (HAS_EXP || HAS_PSUM2) {
    // sum across the 16 lanes sharing the same rows (lane bits 0-3 vary col)
    #pragma unroll
    for (int msk = 1; msk < 16; msk <<= 1)
      #pragma unroll
      for (int mi = 0; mi < 4; mi++)
        #pragma unroll
        for (int r = 0; r < 4; r++) {
          rowsum[mi][r] += __shfl_xor(rowsum[mi][r], msk);
          if (HAS_PSUM2) rowsq[mi][r] += __shfl_xor(rowsq[mi][r], msk);
        }
    if ((lane & 15) == 0) {
      #pragma unroll
      for (int mi = 0; mi < 4; mi++)
        #pragma unroll
        for (int r = 0; r < 4; r++) {
          psum[wave & 1][wm + mi * 16 + dr + r] = rowsum[mi][r];
          if (HAS_PSUM2) psum[2 + (wave & 1)][wm + mi * 16 + dr + r] = rowsq[mi][r];
        }
    }
    __syncthreads();
    if (tid < 128) {
      if (HAS_EXP)
        psum_out[((long)blockIdx.z * gridDim.x + blockIdx.x) * 4096 + bm + tid] =
            psum[0][tid] + psum[1][tid];
      if (HAS_PSUM2) {
        const long blk = ((long)blockIdx.z * gridDim.y + blockIdx.y) * gridDim.x
                         + blockIdx.x;
        psum_out[blk * 256 + tid] = psum[0][tid] + psum[1][tid];
        psum_out[blk * 256 + 128 + tid] = psum[2][tid] + psum[3][tid];
      }
    }
  }
}

// ---------------- inv[b][n] = 1 / sum_x partial[b][x][n] ----------------
__global__ __launch_bounds__(256) void inv_kernel(const float* __restrict__ partial,
                                                  float* __restrict__ inv) {
  const int idx = blockIdx.x * 256 + threadIdx.x;   // b*4096+n
  const int b = idx >> 12, n = idx & 4095;
  const float* p = partial + (long)b * 32768 + n;
  float s = 0.f;
  #pragma unroll
  for (int x = 0; x < 8; x++) s += p[(long)x * 4096];
  inv[idx] = 1.0f / s;
}

// ---------------- gbar[b][d] = mean over m of g_n[b][d][:] ----------------
__global__ __launch_bounds__(256) void gbar_kernel(const u16* __restrict__ g_n,
                                                   float* __restrict__ gbar) {
  const int row = blockIdx.x * 4 + (threadIdx.x >> 6);   // 0..4095 = b*512+d
  const int lane = threadIdx.x & 63;
  const long base = (long)row * MPIX + lane * 16;
  uint4 va = *(const uint4*)(g_n + base);
  uint4 vb = *(const uint4*)(g_n + base + 8);
  float f[16];
  unpack8(va, f); unpack8(vb, f + 8);
  float s = 0.f;
  #pragma unroll
  for (int j = 0; j < 16; j++) s += f[j];
  #pragma unroll
  for (int off = 32; off > 0; off >>= 1) s += __shfl_xor(s, off);
  if (lane == 0) gbar[row] = s * (1.0f / 1024.0f);
}

// ------- c0[b][c] = out_b[c] + sum_d out_w_f32[c][d]*gbar[b][d] ----------
__global__ __launch_bounds__(256) void c0_kernel(const float* __restrict__ out_w,
                                                 const float* __restrict__ out_b,
                                                 const float* __restrict__ gbar,
                                                 float* __restrict__ c0) {
  const int idx = blockIdx.x * 4 + (threadIdx.x >> 6);   // 0..8191 = b*1024+c
  const int lane = threadIdx.x & 63;
  const int b = idx >> 10, c = idx & 1023;
  const int d0 = lane * 8;
  float4 w0 = *(const float4*)(out_w + (long)c * DI + d0);
  float4 w1 = *(const float4*)(out_w + (long)c * DI + d0 + 4);
  float4 g0 = *(const float4*)(gbar + (long)b * DI + d0);
  float4 g1 = *(const float4*)(gbar + (long)b * DI + d0 + 4);
  float s = w0.x * g0.x + w0.y * g0.y + w0.z * g0.z + w0.w * g0.w
          + w1.x * g1.x + w1.y * g1.y + w1.z * g1.z + w1.w * g1.w;
  #pragma unroll
  for (int off = 32; off > 0; off >>= 1) s += __shfl_xor(s, off);
  if (lane == 0) c0[idx] = out_b[c] + s;
}

// ------ BN stats from y-GEMM per-block partials + c0 ---------------------
// partial blk layout: blk = ((b*8 + by)*32 + bx), [0..127]=sum, [128..255]=sq
__global__ __launch_bounds__(256) void stats2_kernel(const float* __restrict__ partial,
                                                     const float* __restrict__ c0,
                                                     float* __restrict__ stats) {
  const int co = blockIdx.x * 256 + threadIdx.x;  // 0..1023
  const int by = co >> 7, r = co & 127;
  float sd = 0.f, sd2 = 0.f, sbc = 0.f;
  for (int b = 0; b < 8; b++) {
    float sb = 0.f, qb = 0.f;
    #pragma unroll
    for (int bx = 0; bx < 32; bx++) {
      const long blk = (((long)b * 8 + by) * 32 + bx) * 256;
      sb += partial[blk + r];
      qb += partial[blk + 128 + r];
    }
    sd += sb; sd2 += qb;
    sbc += c0[b * 1024 + co] * sb;
  }
  float sc0 = 0.f, sc02 = 0.f;
  #pragma unroll
  for (int b = 0; b < 8; b++) {
    float c = c0[b * 1024 + co];
    sc0 += c; sc02 += c * c;
  }
  stats[co] = 4096.0f * sc0 + sd;
  stats[1024 + co] = 4096.0f * sc02 + 2.0f * sbc + sd2;
}

// ---------------- BN apply + residual (bf16 dy + c0) ----------------
__global__ __launch_bounds__(256) void final_kernel(const u16* __restrict__ dy,
    const float* __restrict__ x, const float* __restrict__ stats,
    const float* __restrict__ c0,
    const float* __restrict__ bnw, const float* __restrict__ bnb,
    float* __restrict__ out) {
  const int bc = blockIdx.x;
  const int co = bc & 1023;
  const float mean = stats[co] * (1.0f / 32768.0f);
  const float var = stats[1024 + co] * (1.0f / 32768.0f) - mean * mean;
  const float inv = rsqrtf(var + 1e-5f) * bnw[co];
  const float addc = bnb[co] - mean * inv + c0[bc] * inv;
  const long base = (long)bc * 4096;
  const int t = threadIdx.x;
  #pragma unroll
  for (int i = 0; i < 2; i++) {
    const long off = base + (long)(i * 256 + t) * 8;
    uint4 v = *(const uint4*)(dy + off);
    float f[8]; unpack8(v, f);
    const float4 x0 = *(const float4*)(x + off);
    const float4 x1 = *(const float4*)(x + off + 4);
    float4 o0, o1;
    o0.x = f[0] * inv + addc + x0.x;
    o0.y = f[1] * inv + addc + x0.y;
    o0.z = f[2] * inv + addc + x0.z;
    o0.w = f[3] * inv + addc + x0.w;
    o1.x = f[4] * inv + addc + x1.x;
    o1.y = f[5] * inv + addc + x1.y;
    o1.z = f[6] * inv + addc + x1.z;
    o1.w = f[7] * inv + addc + x1.w;
    *(float4*)(out + off) = o0;
    *(float4*)(out + off + 4) = o1;
  }
}

extern "C" void kernel_launch(void* const* d_in, const int* in_sizes, int n_in,
                              void* d_out, int out_size, void* d_ws, size_t ws_size,
                              hipStream_t stream) {
  (void)in_sizes; (void)n_in; (void)out_size; (void)ws_size;
  const float* x       = (const float*)d_in[0];
  const float* theta_w = (const float*)d_in[1];
  const float* theta_b = (const float*)d_in[2];
  const float* phi_w   = (const float*)d_in[3];
  const float* phi_b   = (const float*)d_in[4];
  const float* g_w     = (const float*)d_in[5];
  const float* g_b     = (const float*)d_in[6];
  const float* out_w   = (const float*)d_in[7];
  const float* out_b   = (const float*)d_in[8];
  const float* bn_w    = (const float*)d_in[9];
  const float* bn_b    = (const float*)d_in[10];
  float* out = (float*)d_out;
  char* ws = (char*)d_ws;
  const size_t MB = 1024 * 1024;

  // workspace layout
  u16* xT     = (u16*)(ws + 0 * MB);       // 64MB; later: dy bf16 [0,64MB)
  u16* poolT  = (u16*)(ws + 64 * MB);      // 16MB
  u16* w_th   = (u16*)(ws + 80 * MB);      // 1MB
  u16* w_ph   = (u16*)(ws + 81 * MB);      // 1MB
  u16* w_g    = (u16*)(ws + 82 * MB);      // 1MB
  u16* thetaT = (u16*)(ws + 84 * MB);      // 32MB
  u16* phiT   = (u16*)(ws + 116 * MB);     // 8MB
  u16* g_n    = (u16*)(ws + 124 * MB);     // 8MB
  u16* e      = (u16*)(ws + 132 * MB);     // 64MB (exp(scores))
  u16* tT     = (u16*)(ws + 196 * MB);     // 32MB (delta-t bf16)
  u16* w_out  = (u16*)(ws + 228 * MB);     // 1MB
  float* inv_s = (float*)(ws + 229 * MB);            // 128KB
  float* gbar  = (float*)(ws + 229 * MB + 131072);   // 16KB
  float* c0b   = (float*)(ws + 229 * MB + 147456);   // 32KB
  float* stats = (float*)(ws + 229 * MB + 180224);   // 8KB
  float* partial = (float*)(ws + 230 * MB);          // 1MB (8*8*4096 f32)
  float* partial2 = (float*)(ws + 231 * MB);         // 2MB (2048 blk * 256 f32)
  u16* dy = xT;               // alias: x_T dead after theta GEMM

  // 1. weights -> bf16 (single launch)
  cvt4_kernel<<<2048, 256, 0, stream>>>(theta_w, phi_w, g_w, out_w,
                                        w_th, w_ph, w_g, w_out);
  // 2. x -> x_T bf16 with fused 2x2 maxpool
  transpose_pool_kernel<<<dim3(32, 16, 8), 256, 0, stream>>>(x, xT, poolT);
  // 4. theta -> theta_T [b][4096][512]
  gemm_tn<1, true, false, false, false, false><<<dim3(32, 4, 8), 256, 0, stream>>>(
      w_th, xT, thetaT, theta_b, 0L, nullptr, 0L, nullptr, 0L, nullptr,
      1.0f, 512, 4096, 1024, 0L, (long)NPIX * CIN, (long)NPIX * DI);
  // 5. phi -> phi_T [b][1024][512]
  gemm_tn<1, true, false, false, false, false><<<dim3(8, 4, 8), 256, 0, stream>>>(
      w_ph, poolT, phiT, phi_b, 0L, nullptr, 0L, nullptr, 0L, nullptr,
      1.0f, 512, 1024, 1024, 0L, (long)MPIX * CIN, (long)MPIX * DI);
  // 6. g -> g_n [b][512][1024]
  gemm_tn<0, true, false, false, false, false><<<dim3(8, 4, 8), 256, 0, stream>>>(
      w_g, poolT, g_n, g_b, 0L, nullptr, 0L, nullptr, 0L, nullptr,
      1.0f, 512, 1024, 1024, 0L, (long)MPIX * CIN, (long)DI * MPIX);
  // 6b. gbar[b][d] ; c0[b][c] (f32 path for the constant part of t)
  gbar_kernel<<<1024, 256, 0, stream>>>(g_n, gbar);
  c0_kernel<<<2048, 256, 0, stream>>>(out_w, out_b, gbar, c0b);
  // 7. e[n][m] = exp(theta_T*phi_T^T * scale) + per-block rowsum partials
  gemm_tn<0, false, false, false, true, false><<<dim3(8, 32, 8), 256, 0, stream>>>(
      thetaT, phiT, e, nullptr, 0L, nullptr, 0L, nullptr, 0L, partial,
      0.044194173824159216f, 4096, 1024, 512,
      (long)NPIX * DI, (long)MPIX * DI, (long)NPIX * MPIX);
  // 8. inv[b][n] = 1/rowsum
  inv_kernel<<<128, 256, 0, stream>>>(partial, inv_s);
  // 9. delta-t[d][n] = (g_n * e^T)*inv_s[n] - gbar[d] -> tT bf16 [b][4096][512]
  gemm_tn<1, false, true, true, false, false><<<dim3(32, 4, 8), 256, 0, stream>>>(
      g_n, e, tT, nullptr, 0L, inv_s, 4096L, gbar, 512L, nullptr,
      1.0f, 512, 4096, 1024,
      (long)DI * MPIX, (long)NPIX * MPIX, (long)NPIX * DI);
  // 10. dy[co][n] = out_w * delta-t^T -> dy (aliases xT) + BN partials
  gemm_tn<0, false, false, false, false, true><<<dim3(32, 8, 8), 256, 0, stream>>>(
      w_out, tT, dy, nullptr, 0L, nullptr, 0L, nullptr, 0L, partial2,
      1.0f, 1024, 4096, 512, 0L, (long)NPIX * DI, (long)1024 * NPIX);
  // 11. BN stats from partials + c0 (deterministic)
  stats2_kernel<<<4, 256, 0, stream>>>(partial2, c0b, stats);
  // 12. BN apply + residual
  final_kernel<<<8192, 256, 0, stream>>>(dy, x, stats, c0b, bn_w, bn_b, out);
}

// Round 7
// 384.316 us; speedup vs baseline: 1.0082x; 1.0082x over previous
//
#include <hip/hip_runtime.h>
#include <cstdint>

typedef unsigned short u16;
typedef __attribute__((ext_vector_type(4))) unsigned short u16x4;
typedef __attribute__((ext_vector_type(8))) short short8;
typedef __attribute__((ext_vector_type(4))) float f32x4;

#define DI 512
#define CIN 1024
#define NPIX 4096   // 64*64
#define MPIX 1024   // 32*32

__device__ __forceinline__ float bf2f(u16 u) {
  union { unsigned int i; float f; } v; v.i = ((unsigned int)u) << 16; return v.f;
}
__device__ __forceinline__ u16 f2bf(float f) {
  union { float f; unsigned int i; } v; v.f = f;
  unsigned int r = v.i + 0x7fffu + ((v.i >> 16) & 1u);
  return (u16)(r >> 16);
}
__device__ __forceinline__ void unpack8(uint4 v, float* f) {
  union { unsigned int i; float f; } u;
  u.i = v.x << 16;          f[0] = u.f;
  u.i = v.x & 0xffff0000u;  f[1] = u.f;
  u.i = v.y << 16;          f[2] = u.f;
  u.i = v.y & 0xffff0000u;  f[3] = u.f;
  u.i = v.z << 16;          f[4] = u.f;
  u.i = v.z & 0xffff0000u;  f[5] = u.f;
  u.i = v.w << 16;          f[6] = u.f;
  u.i = v.w & 0xffff0000u;  f[7] = u.f;
}

// async global->LDS, 16B per lane, wave-uniform LDS base + lane*16
__device__ __forceinline__ void gload16(const u16* g, u16* l) {
  __builtin_amdgcn_global_load_lds(
      (const __attribute__((address_space(1))) void*)g,
      (__attribute__((address_space(3))) void*)l, 16, 0, 0);
}

// ---------------- f32 -> bf16 convert (4 weight tensors in one launch) ----
__global__ __launch_bounds__(256) void cvt4_kernel(
    const float* __restrict__ s0, const float* __restrict__ s1,
    const float* __restrict__ s2, const float* __restrict__ s3,
    u16* __restrict__ d0, u16* __restrict__ d1,
    u16* __restrict__ d2, u16* __restrict__ d3) {
  int i = blockIdx.x * 256 + threadIdx.x;     // 0 .. 4*131072
  int sel = i >> 17;
  int j = i & 131071;
  const float* src = sel == 0 ? s0 : sel == 1 ? s1 : sel == 2 ? s2 : s3;
  u16* dst = sel == 0 ? d0 : sel == 1 ? d1 : sel == 2 ? d2 : d3;
  float4 v = *(const float4*)(src + (long)j * 4);
  u16x4 w;
  w[0] = f2bf(v.x); w[1] = f2bf(v.y); w[2] = f2bf(v.z); w[3] = f2bf(v.w);
  *(u16x4*)(dst + (long)j * 4) = w;
}

// ---------------- x [b][c][n] f32 -> x_T [b][n][c] bf16 ----------------
__global__ __launch_bounds__(256) void transpose_kernel(const float* __restrict__ x,
                                                        u16* __restrict__ xT) {
  __shared__ u16 tile[64][72];
  const int b = blockIdx.z;
  const int n0 = blockIdx.x * 64, c0 = blockIdx.y * 64;
  const float* xb = x + (long)b * CIN * NPIX;
  u16* xTb = xT + (long)b * NPIX * CIN;
  const int t = threadIdx.x;
  const int tc = t >> 4, tn = (t & 15) * 4;
  #pragma unroll
  for (int i = 0; i < 4; i++) {
    int c = tc + i * 16;
    float4 v = *(const float4*)(xb + (long)(c0 + c) * NPIX + n0 + tn);
    tile[c][tn + 0] = f2bf(v.x);
    tile[c][tn + 1] = f2bf(v.y);
    tile[c][tn + 2] = f2bf(v.z);
    tile[c][tn + 3] = f2bf(v.w);
  }
  __syncthreads();
  const int tn2 = t >> 4, tc2 = (t & 15) * 4;
  #pragma unroll
  for (int i = 0; i < 4; i++) {
    int n = tn2 + i * 16;
    u16x4 w;
    w[0] = tile[tc2 + 0][n];
    w[1] = tile[tc2 + 1][n];
    w[2] = tile[tc2 + 2][n];
    w[3] = tile[tc2 + 3][n];
    *(u16x4*)(xTb + (long)(n0 + n) * CIN + c0 + tc2) = w;
  }
}

// ---------------- 2x2 maxpool in transposed layout ----------------
__global__ __launch_bounds__(256) void pool_kernel(const u16* __restrict__ xT,
                                                   u16* __restrict__ poolT) {
  const int idx = blockIdx.x * 256 + threadIdx.x;
  const int cc = (idx & 127) * 8;
  const int m = (idx >> 7) & 1023;
  const int b = idx >> 17;
  const int i = m >> 5, j = m & 31;
  const int n1 = (i * 2) * 64 + j * 2;
  const u16* base = xT + (long)b * NPIX * CIN + cc;
  uint4 v0 = *(const uint4*)(base + (long)(n1) * CIN);
  uint4 v1 = *(const uint4*)(base + (long)(n1 + 1) * CIN);
  uint4 v2 = *(const uint4*)(base + (long)(n1 + 64) * CIN);
  uint4 v3 = *(const uint4*)(base + (long)(n1 + 65) * CIN);
  float f0[8], f1[8], f2[8], f3[8];
  unpack8(v0, f0); unpack8(v1, f1); unpack8(v2, f2); unpack8(v3, f3);
  u16 r[8] __attribute__((aligned(16)));
  #pragma unroll
  for (int k = 0; k < 8; k++) {
    float mx = fmaxf(fmaxf(f0[k], f1[k]), fmaxf(f2[k], f3[k]));
    r[k] = f2bf(mx);
  }
  *(uint4*)(poolT + ((long)b * MPIX + m) * CIN + cc) = *(uint4*)r;
}

// ---------------- GEMM: C[M][N] = A[M][K] * B[N][K]^T ----
// global_load_lds staging, linear LDS [128][64] bf16, XOR-swizzled 16B slots.
// OM: 0 = bf16 plain [M][N], 1 = bf16 transposed [N][M].
// Epilogue stages the 128x128 bf16 tile through LDS (reusing As/Bs) so all
// global C-writes are coalesced 16B/lane.
// HAS_EXP: v = exp(acc*scale); writes per-block row-sums to
//          psum_out[(z*gridX + x)*4096 + row].
// HAS_PSUM2: writes per-block row (sum, sumsq) to
//          psum_out[blk*256 + {row, 128+row}], blk = (z*gridY+y)*gridX+x.
template<int OM, bool HAS_BIAS, bool HAS_CS, bool HAS_SHIFT, bool HAS_EXP, bool HAS_PSUM2>
__global__ __launch_bounds__(256)
void gemm_tn(const u16* __restrict__ A, const u16* __restrict__ B,
             void* __restrict__ Cv,
             const float* __restrict__ bias, long sBias,
             const float* __restrict__ cs, long sCS,
             const float* __restrict__ shift, long sShift,
             float* __restrict__ psum_out,
             float scale, int M, int N, int K, long sA, long sB, long sC)
{
  A += blockIdx.z * sA;
  B += blockIdx.z * sB;
  if (HAS_BIAS) bias += blockIdx.z * sBias;
  if (HAS_CS) cs += blockIdx.z * sCS;
  if (HAS_SHIFT) shift += blockIdx.z * sShift;
  const int bm = blockIdx.y * 128;
  const int bn = blockIdx.x * 128;
  __shared__ __align__(16) u16 smem[128 * 128];   // As=[0,8K), Bs=[8K,16K) u16
  u16* As = smem;
  u16* Bs = smem + 128 * 64;
  __shared__ float psum[4][128];
  const int tid = threadIdx.x;
  const int lane = tid & 63;
  const int wave = tid >> 6;
  const int wm = (wave >> 1) * 64;
  const int wn = (wave & 1) * 64;
  const int lr = lane & 15;          // frag row (A) / col (B,D)
  const int q  = lane >> 4;          // 16B slot quarter within k
  const int sxor = lane & 7;
  f32x4 acc[4][4] = {};

  const int swz = ((lane & 7) ^ (lane >> 3)) * 8;
  const long grow = 32 * wave + (lane >> 3);
  const u16* Ag = A + ((long)bm + grow) * K + swz;
  const u16* Bg = B + ((long)bn + grow) * K + swz;

  for (int kt = 0; kt < K; kt += 64) {
    __syncthreads();
    #pragma unroll
    for (int i = 0; i < 4; i++) {
      gload16(Ag + (long)(8 * i) * K + kt, &As[(wave * 4 + i) * 512]);
      gload16(Bg + (long)(8 * i) * K + kt, &Bs[(wave * 4 + i) * 512]);
    }
    __syncthreads();
    #pragma unroll
    for (int kk = 0; kk < 2; kk++) {
      short8 av[4], bv[4];
      #pragma unroll
      for (int mi = 0; mi < 4; mi++)
        av[mi] = *(const short8*)&As[(wm + mi * 16 + lr) * 64 +
                                     (((kk << 2) + q) ^ sxor) * 8];
      #pragma unroll
      for (int ni = 0; ni < 4; ni++)
        bv[ni] = *(const short8*)&Bs[(wn + ni * 16 + lr) * 64 +
                                     (((kk << 2) + q) ^ sxor) * 8];
      #pragma unroll
      for (int mi = 0; mi < 4; mi++) {
        #pragma unroll
        for (int ni = 0; ni < 4; ni++)
          acc[mi][ni] = __builtin_amdgcn_mfma_f32_16x16x32_bf16(
              av[mi], bv[ni], acc[mi][ni], 0, 0, 0);
      }
    }
  }

  // ---------------- epilogue: stage 128x128 bf16 tile in LDS ------------
  __syncthreads();   // all waves done with As/Bs ds_reads
  const int dr = (lane >> 4) * 4;
  float rowsum[4][4];
  float rowsq[4][4];
  if (HAS_EXP || HAS_PSUM2) {
    #pragma unroll
    for (int mi = 0; mi < 4; mi++)
      #pragma unroll
      for (int r = 0; r < 4; r++) { rowsum[mi][r] = 0.f; rowsq[mi][r] = 0.f; }
  }
  #pragma unroll
  for (int mi = 0; mi < 4; mi++) {
    const int rowl = wm + mi * 16 + dr;      // local row base
    const int rowb = bm + rowl;              // global row base
    float bvs[4] = {0.f, 0.f, 0.f, 0.f};
    float shv[4] = {0.f, 0.f, 0.f, 0.f};
    if (HAS_BIAS) {
      #pragma unroll
      for (int r = 0; r < 4; r++) bvs[r] = bias[rowb + r];
    }
    if (HAS_SHIFT) {
      #pragma unroll
      for (int r = 0; r < 4; r++) shv[r] = shift[rowb + r];
    }
    #pragma unroll
    for (int ni = 0; ni < 4; ni++) {
      const int coll = wn + ni * 16 + lr;    // local col
      const float csv = HAS_CS ? cs[bn + coll] : 1.0f;
      float v[4];
      #pragma unroll
      for (int r = 0; r < 4; r++) {
        float t = acc[mi][ni][r] * scale;
        if (HAS_CS) t *= csv;
        if (HAS_SHIFT) t -= shv[r];
        if (HAS_BIAS) t += bvs[r];
        if (HAS_EXP) t = expf(t);
        if (HAS_EXP || HAS_PSUM2) rowsum[mi][r] += t;
        if (HAS_PSUM2) rowsq[mi][r] += t * t;
        v[r] = t;
      }
      if (OM == 1) {
        // [col][row] layout, byte-XOR swizzle on bits 4-6
        u16x4 w;
        #pragma unroll
        for (int r = 0; r < 4; r++) w[r] = f2bf(v[r]);
        unsigned bo = (unsigned)((coll * 128 + rowl) * 2) ^ ((coll & 7) << 4);
        *(u16x4*)((char*)smem + bo) = w;
      } else {
        // [row][col] layout, scalar writes (banks spread by col/2: free)
        #pragma unroll
        for (int r = 0; r < 4; r++) smem[(rowl + r) * 128 + coll] = f2bf(v[r]);
      }
    }
  }
  if (HAS_EXP || HAS_PSUM2) {
    // sum across the 16 lanes sharing the same rows (lane bits 0-3 vary col)
    #pragma unroll
    for (int msk = 1; msk < 16; msk <<= 1)
      #pragma unroll
      for (int mi = 0; mi < 4; mi++)
        #pragma unroll
        for (int r = 0; r < 4; r++) {
          rowsum[mi][r] += __shfl_xor(rowsum[mi][r], msk);
          if (HAS_PSUM2) rowsq[mi][r] += __shfl_xor(rowsq[mi][r], msk);
        }
    if ((lane & 15) == 0) {
      #pragma unroll
      for (int mi = 0; mi < 4; mi++)
        #pragma unroll
        for (int r = 0; r < 4; r++) {
          psum[wave & 1][wm + mi * 16 + dr + r] = rowsum[mi][r];
          if (HAS_PSUM2) psum[2 + (wave & 1)][wm + mi * 16 + dr + r] = rowsq[mi][r];
        }
    }
  }
  __syncthreads();
  // coalesced flush: 8 x (ds_read_b128 + global_store_dwordx4) per thread
  u16* C = (u16*)Cv + blockIdx.z * sC;
  if (OM == 1) {
    #pragma unroll
    for (int i = 0; i < 8; i++) {
      const int chunk = i * 256 + tid;
      const int coll = chunk >> 4, rq = chunk & 15;
      unsigned bo = (unsigned)(coll * 256 + rq * 16) ^ ((coll & 7) << 4);
      uint4 w = *(const uint4*)((const char*)smem + bo);
      *(uint4*)(C + (long)(bn + coll) * M + bm + rq * 8) = w;
    }
  } else {
    #pragma unroll
    for (int i = 0; i < 8; i++) {
      const int chunk = i * 256 + tid;
      const int row = chunk >> 4, cq = chunk & 15;
      uint4 w = *(const uint4*)(smem + row * 128 + cq * 8);
      *(uint4*)(C + (long)(bm + row) * N + bn + cq * 8) = w;
    }
  }
  if (HAS_EXP || HAS_PSUM2) {
    if (tid < 128) {
      if (HAS_EXP)
        psum_out[((long)blockIdx.z * gridDim.x + blockIdx.x) * 4096 + bm + tid] =
            psum[0][tid] + psum[1][tid];
      if (HAS_PSUM2) {
        const long blk = ((long)blockIdx.z * gridDim.y + blockIdx.y) * gridDim.x
                         + blockIdx.x;
        psum_out[blk * 256 + tid] = psum[0][tid] + psum[1][tid];
        psum_out[blk * 256 + 128 + tid] = psum[2][tid] + psum[3][tid];
      }
    }
  }
}

// ---------------- inv[b][n] = 1 / sum_x partial[b][x][n] ----------------
__global__ __launch_bounds__(256) void inv_kernel(const float* __restrict__ partial,
                                                  float* __restrict__ inv) {
  const int idx = blockIdx.x * 256 + threadIdx.x;   // b*4096+n
  const int b = idx >> 12, n = idx & 4095;
  const float* p = partial + (long)b * 32768 + n;
  float s = 0.f;
  #pragma unroll
  for (int x = 0; x < 8; x++) s += p[(long)x * 4096];
  inv[idx] = 1.0f / s;
}

// ---------------- gbar[b][d] = mean over m of g_n[b][d][:] ----------------
__global__ __launch_bounds__(256) void gbar_kernel(const u16* __restrict__ g_n,
                                                   float* __restrict__ gbar) {
  const int row = blockIdx.x * 4 + (threadIdx.x >> 6);   // 0..4095 = b*512+d
  const int lane = threadIdx.x & 63;
  const long base = (long)row * MPIX + lane * 16;
  uint4 va = *(const uint4*)(g_n + base);
  uint4 vb = *(const uint4*)(g_n + base + 8);
  float f[16];
  unpack8(va, f); unpack8(vb, f + 8);
  float s = 0.f;
  #pragma unroll
  for (int j = 0; j < 16; j++) s += f[j];
  #pragma unroll
  for (int off = 32; off > 0; off >>= 1) s += __shfl_xor(s, off);
  if (lane == 0) gbar[row] = s * (1.0f / 1024.0f);
}

// ------- c0[b][c] = out_b[c] + sum_d out_w_f32[c][d]*gbar[b][d] ----------
__global__ __launch_bounds__(256) void c0_kernel(const float* __restrict__ out_w,
                                                 const float* __restrict__ out_b,
                                                 const float* __restrict__ gbar,
                                                 float* __restrict__ c0) {
  const int idx = blockIdx.x * 4 + (threadIdx.x >> 6);   // 0..8191 = b*1024+c
  const int lane = threadIdx.x & 63;
  const int b = idx >> 10, c = idx & 1023;
  const int d0 = lane * 8;
  float4 w0 = *(const float4*)(out_w + (long)c * DI + d0);
  float4 w1 = *(const float4*)(out_w + (long)c * DI + d0 + 4);
  float4 g0 = *(const float4*)(gbar + (long)b * DI + d0);
  float4 g1 = *(const float4*)(gbar + (long)b * DI + d0 + 4);
  float s = w0.x * g0.x + w0.y * g0.y + w0.z * g0.z + w0.w * g0.w
          + w1.x * g1.x + w1.y * g1.y + w1.z * g1.z + w1.w * g1.w;
  #pragma unroll
  for (int off = 32; off > 0; off >>= 1) s += __shfl_xor(s, off);
  if (lane == 0) c0[idx] = out_b[c] + s;
}

// ------ BN stats from y-GEMM per-block partials + c0 ---------------------
// partial blk layout: blk = ((b*8 + by)*32 + bx), [0..127]=sum, [128..255]=sq
__global__ __launch_bounds__(256) void stats2_kernel(const float* __restrict__ partial,
                                                     const float* __restrict__ c0,
                                                     float* __restrict__ stats) {
  const int co = blockIdx.x * 256 + threadIdx.x;  // 0..1023
  const int by = co >> 7, r = co & 127;
  float sd = 0.f, sd2 = 0.f, sbc = 0.f;
  for (int b = 0; b < 8; b++) {
    float sb = 0.f, qb = 0.f;
    #pragma unroll
    for (int bx = 0; bx < 32; bx++) {
      const long blk = (((long)b * 8 + by) * 32 + bx) * 256;
      sb += partial[blk + r];
      qb += partial[blk + 128 + r];
    }
    sd += sb; sd2 += qb;
    sbc += c0[b * 1024 + co] * sb;
  }
  float sc0 = 0.f, sc02 = 0.f;
  #pragma unroll
  for (int b = 0; b < 8; b++) {
    float c = c0[b * 1024 + co];
    sc0 += c; sc02 += c * c;
  }
  stats[co] = 4096.0f * sc0 + sd;
  stats[1024 + co] = 4096.0f * sc02 + 2.0f * sbc + sd2;
}

// ---------------- BN apply + residual (bf16 dy + c0) ----------------
__global__ __launch_bounds__(256) void final_kernel(const u16* __restrict__ dy,
    const float* __restrict__ x, const float* __restrict__ stats,
    const float* __restrict__ c0,
    const float* __restrict__ bnw, const float* __restrict__ bnb,
    float* __restrict__ out) {
  const int bc = blockIdx.x;
  const int co = bc & 1023;
  const float mean = stats[co] * (1.0f / 32768.0f);
  const float var = stats[1024 + co] * (1.0f / 32768.0f) - mean * mean;
  const float inv = rsqrtf(var + 1e-5f) * bnw[co];
  const float addc = bnb[co] - mean * inv + c0[bc] * inv;
  const long base = (long)bc * 4096;
  const int t = threadIdx.x;
  #pragma unroll
  for (int i = 0; i < 2; i++) {
    const long off = base + (long)(i * 256 + t) * 8;
    uint4 v = *(const uint4*)(dy + off);
    float f[8]; unpack8(v, f);
    const float4 x0 = *(const float4*)(x + off);
    const float4 x1 = *(const float4*)(x + off + 4);
    float4 o0, o1;
    o0.x = f[0] * inv + addc + x0.x;
    o0.y = f[1] * inv + addc + x0.y;
    o0.z = f[2] * inv + addc + x0.z;
    o0.w = f[3] * inv + addc + x0.w;
    o1.x = f[4] * inv + addc + x1.x;
    o1.y = f[5] * inv + addc + x1.y;
    o1.z = f[6] * inv + addc + x1.z;
    o1.w = f[7] * inv + addc + x1.w;
    *(float4*)(out + off) = o0;
    *(float4*)(out + off + 4) = o1;
  }
}

extern "C" void kernel_launch(void* const* d_in, const int* in_sizes, int n_in,
                              void* d_out, int out_size, void* d_ws, size_t ws_size,
                              hipStream_t stream) {
  (void)in_sizes; (void)n_in; (void)out_size; (void)ws_size;
  const float* x       = (const float*)d_in[0];
  const float* theta_w = (const float*)d_in[1];
  const float* theta_b = (const float*)d_in[2];
  const float* phi_w   = (const float*)d_in[3];
  const float* phi_b   = (const float*)d_in[4];
  const float* g_w     = (const float*)d_in[5];
  const float* g_b     = (const float*)d_in[6];
  const float* out_w   = (const float*)d_in[7];
  const float* out_b   = (const float*)d_in[8];
  const float* bn_w    = (const float*)d_in[9];
  const float* bn_b    = (const float*)d_in[10];
  float* out = (float*)d_out;
  char* ws = (char*)d_ws;
  const size_t MB = 1024 * 1024;

  // workspace layout
  u16* xT     = (u16*)(ws + 0 * MB);       // 64MB; later: dy bf16 [0,64MB)
  u16* poolT  = (u16*)(ws + 64 * MB);      // 16MB
  u16* w_th   = (u16*)(ws + 80 * MB);      // 1MB
  u16* w_ph   = (u16*)(ws + 81 * MB);      // 1MB
  u16* w_g    = (u16*)(ws + 82 * MB);      // 1MB
  u16* thetaT = (u16*)(ws + 84 * MB);      // 32MB
  u16* phiT   = (u16*)(ws + 116 * MB);     // 8MB
  u16* g_n    = (u16*)(ws + 124 * MB);     // 8MB
  u16* e      = (u16*)(ws + 132 * MB);     // 64MB (exp(scores))
  u16* tT     = (u16*)(ws + 196 * MB);     // 32MB (delta-t bf16)
  u16* w_out  = (u16*)(ws + 228 * MB);     // 1MB
  float* inv_s = (float*)(ws + 229 * MB);            // 128KB
  float* gbar  = (float*)(ws + 229 * MB + 131072);   // 16KB
  float* c0b   = (float*)(ws + 229 * MB + 147456);   // 32KB
  float* stats = (float*)(ws + 229 * MB + 180224);   // 8KB
  float* partial = (float*)(ws + 230 * MB);          // 1MB (8*8*4096 f32)
  float* partial2 = (float*)(ws + 231 * MB);         // 2MB (2048 blk * 256 f32)
  u16* dy = xT;               // alias: x_T dead after theta GEMM

  // 1. weights -> bf16 (single launch)
  cvt4_kernel<<<2048, 256, 0, stream>>>(theta_w, phi_w, g_w, out_w,
                                        w_th, w_ph, w_g, w_out);
  // 2. x -> x_T bf16 ; 3. pool
  transpose_kernel<<<dim3(64, 16, 8), 256, 0, stream>>>(x, xT);
  pool_kernel<<<4096, 256, 0, stream>>>(xT, poolT);
  // 4. theta -> theta_T [b][4096][512]
  gemm_tn<1, true, false, false, false, false><<<dim3(32, 4, 8), 256, 0, stream>>>(
      w_th, xT, thetaT, theta_b, 0L, nullptr, 0L, nullptr, 0L, nullptr,
      1.0f, 512, 4096, 1024, 0L, (long)NPIX * CIN, (long)NPIX * DI);
  // 5. phi -> phi_T [b][1024][512]
  gemm_tn<1, true, false, false, false, false><<<dim3(8, 4, 8), 256, 0, stream>>>(
      w_ph, poolT, phiT, phi_b, 0L, nullptr, 0L, nullptr, 0L, nullptr,
      1.0f, 512, 1024, 1024, 0L, (long)MPIX * CIN, (long)MPIX * DI);
  // 6. g -> g_n [b][512][1024]
  gemm_tn<0, true, false, false, false, false><<<dim3(8, 4, 8), 256, 0, stream>>>(
      w_g, poolT, g_n, g_b, 0L, nullptr, 0L, nullptr, 0L, nullptr,
      1.0f, 512, 1024, 1024, 0L, (long)MPIX * CIN, (long)DI * MPIX);
  // 6b. gbar[b][d] ; c0[b][c] (f32 path for the constant part of t)
  gbar_kernel<<<1024, 256, 0, stream>>>(g_n, gbar);
  c0_kernel<<<2048, 256, 0, stream>>>(out_w, out_b, gbar, c0b);
  // 7. e[n][m] = exp(theta_T*phi_T^T * scale) + per-block rowsum partials
  gemm_tn<0, false, false, false, true, false><<<dim3(8, 32, 8), 256, 0, stream>>>(
      thetaT, phiT, e, nullptr, 0L, nullptr, 0L, nullptr, 0L, partial,
      0.044194173824159216f, 4096, 1024, 512,
      (long)NPIX * DI, (long)MPIX * DI, (long)NPIX * MPIX);
  // 8. inv[b][n] = 1/rowsum
  inv_kernel<<<128, 256, 0, stream>>>(partial, inv_s);
  // 9. delta-t[d][n] = (g_n * e^T)*inv_s[n] - gbar[d] -> tT bf16 [b][4096][512]
  gemm_tn<1, false, true, true, false, false><<<dim3(32, 4, 8), 256, 0, stream>>>(
      g_n, e, tT, nullptr, 0L, inv_s, 4096L, gbar, 512L, nullptr,
      1.0f, 512, 4096, 1024,
      (long)DI * MPIX, (long)NPIX * MPIX, (long)NPIX * DI);
  // 10. dy[co][n] = out_w * delta-t^T -> dy (aliases xT) + BN partials
  gemm_tn<0, false, false, false, false, true><<<dim3(32, 8, 8), 256, 0, stream>>>(
      w_out, tT, dy, nullptr, 0L, nullptr, 0L, nullptr, 0L, partial2,
      1.0f, 1024, 4096, 512, 0L, (long)NPIX * DI, (long)1024 * NPIX);
  // 11. BN stats from partials + c0 (deterministic)
  stats2_kernel<<<4, 256, 0, stream>>>(partial2, c0b, stats);
  // 12. BN apply + residual
  final_kernel<<<8192, 256, 0, stream>>>(dy, x, stats, c0b, bn_w, bn_b, out);
}

// Round 8
// 365.161 us; speedup vs baseline: 1.0610x; 1.0525x over previous
//
#include <hip/hip_runtime.h>
#include <cstdint>

typedef unsigned short u16;
typedef __attribute__((ext_vector_type(4))) unsigned short u16x4;
typedef __attribute__((ext_vector_type(8))) short short8;
typedef __attribute__((ext_vector_type(4))) float f32x4;

#define DI 512
#define CIN 1024
#define NPIX 4096   // 64*64
#define MPIX 1024   // 32*32

__device__ __forceinline__ float bf2f(u16 u) {
  union { unsigned int i; float f; } v; v.i = ((unsigned int)u) << 16; return v.f;
}
__device__ __forceinline__ u16 f2bf(float f) {
  union { float f; unsigned int i; } v; v.f = f;
  unsigned int r = v.i + 0x7fffu + ((v.i >> 16) & 1u);
  return (u16)(r >> 16);
}
__device__ __forceinline__ void unpack8(uint4 v, float* f) {
  union { unsigned int i; float f; } u;
  u.i = v.x << 16;          f[0] = u.f;
  u.i = v.x & 0xffff0000u;  f[1] = u.f;
  u.i = v.y << 16;          f[2] = u.f;
  u.i = v.y & 0xffff0000u;  f[3] = u.f;
  u.i = v.z << 16;          f[4] = u.f;
  u.i = v.z & 0xffff0000u;  f[5] = u.f;
  u.i = v.w << 16;          f[6] = u.f;
  u.i = v.w & 0xffff0000u;  f[7] = u.f;
}

// async global->LDS, 16B per lane, wave-uniform LDS base + lane*16
__device__ __forceinline__ void gload16(const u16* g, u16* l) {
  __builtin_amdgcn_global_load_lds(
      (const __attribute__((address_space(1))) void*)g,
      (__attribute__((address_space(3))) void*)l, 16, 0, 0);
}

// ---------------- f32 -> bf16 convert (4 weight tensors in one launch) ----
__global__ __launch_bounds__(256) void cvt4_kernel(
    const float* __restrict__ s0, const float* __restrict__ s1,
    const float* __restrict__ s2, const float* __restrict__ s3,
    u16* __restrict__ d0, u16* __restrict__ d1,
    u16* __restrict__ d2, u16* __restrict__ d3) {
  int i = blockIdx.x * 256 + threadIdx.x;     // 0 .. 4*131072
  int sel = i >> 17;
  int j = i & 131071;
  const float* src = sel == 0 ? s0 : sel == 1 ? s1 : sel == 2 ? s2 : s3;
  u16* dst = sel == 0 ? d0 : sel == 1 ? d1 : sel == 2 ? d2 : d3;
  float4 v = *(const float4*)(src + (long)j * 4);
  u16x4 w;
  w[0] = f2bf(v.x); w[1] = f2bf(v.y); w[2] = f2bf(v.z); w[3] = f2bf(v.w);
  *(u16x4*)(dst + (long)j * 4) = w;
}

// ---------------- x [b][c][n] f32 -> x_T [b][n][c] bf16 ----------------
__global__ __launch_bounds__(256) void transpose_kernel(const float* __restrict__ x,
                                                        u16* __restrict__ xT) {
  __shared__ u16 tile[64][72];
  const int b = blockIdx.z;
  const int n0 = blockIdx.x * 64, c0 = blockIdx.y * 64;
  const float* xb = x + (long)b * CIN * NPIX;
  u16* xTb = xT + (long)b * NPIX * CIN;
  const int t = threadIdx.x;
  const int tc = t >> 4, tn = (t & 15) * 4;
  #pragma unroll
  for (int i = 0; i < 4; i++) {
    int c = tc + i * 16;
    float4 v = *(const float4*)(xb + (long)(c0 + c) * NPIX + n0 + tn);
    tile[c][tn + 0] = f2bf(v.x);
    tile[c][tn + 1] = f2bf(v.y);
    tile[c][tn + 2] = f2bf(v.z);
    tile[c][tn + 3] = f2bf(v.w);
  }
  __syncthreads();
  const int tn2 = t >> 4, tc2 = (t & 15) * 4;
  #pragma unroll
  for (int i = 0; i < 4; i++) {
    int n = tn2 + i * 16;
    u16x4 w;
    w[0] = tile[tc2 + 0][n];
    w[1] = tile[tc2 + 1][n];
    w[2] = tile[tc2 + 2][n];
    w[3] = tile[tc2 + 3][n];
    *(u16x4*)(xTb + (long)(n0 + n) * CIN + c0 + tc2) = w;
  }
}

// ---------------- 2x2 maxpool in transposed layout ----------------
__global__ __launch_bounds__(256) void pool_kernel(const u16* __restrict__ xT,
                                                   u16* __restrict__ poolT) {
  const int idx = blockIdx.x * 256 + threadIdx.x;
  const int cc = (idx & 127) * 8;
  const int m = (idx >> 7) & 1023;
  const int b = idx >> 17;
  const int i = m >> 5, j = m & 31;
  const int n1 = (i * 2) * 64 + j * 2;
  const u16* base = xT + (long)b * NPIX * CIN + cc;
  uint4 v0 = *(const uint4*)(base + (long)(n1) * CIN);
  uint4 v1 = *(const uint4*)(base + (long)(n1 + 1) * CIN);
  uint4 v2 = *(const uint4*)(base + (long)(n1 + 64) * CIN);
  uint4 v3 = *(const uint4*)(base + (long)(n1 + 65) * CIN);
  float f0[8], f1[8], f2[8], f3[8];
  unpack8(v0, f0); unpack8(v1, f1); unpack8(v2, f2); unpack8(v3, f3);
  u16 r[8] __attribute__((aligned(16)));
  #pragma unroll
  for (int k = 0; k < 8; k++) {
    float mx = fmaxf(fmaxf(f0[k], f1[k]), fmaxf(f2[k], f3[k]));
    r[k] = f2bf(mx);
  }
  *(uint4*)(poolT + ((long)b * MPIX + m) * CIN + cc) = *(uint4*)r;
}

// ---------------- GEMM: C[M][N] = A[M][K] * B[N][K]^T ----
// global_load_lds staging, linear LDS [128][64] bf16, XOR-swizzled 16B slots.
// OM: 0 = bf16 plain [M][N], 1 = bf16 transposed [N][M],
//     3 = merged: rows<512 -> transposed (stride 512) to Cv,
//                 rows>=512 -> plain to Cv2 (bias2), g row-partials to psum_out.
// HAS_CSP: col-scale = 1/sum_x cs[x*4096+col] (computed in prologue via LDS).
// HAS_EXP: v = exp(acc*scale); per-block row-sums -> psum_out[(z*gX+x)*4096+row].
// HAS_PSUM2: per-block row (sum,sumsq) -> psum_out[blk*256 + {row,128+row}].
template<int OM, bool HAS_BIAS, bool HAS_CS, bool HAS_SHIFT, bool HAS_EXP,
         bool HAS_PSUM2, bool HAS_CSP>
__global__ __launch_bounds__(256)
void gemm_tn(const u16* __restrict__ A, const u16* __restrict__ B,
             void* __restrict__ Cv, void* __restrict__ Cv2,
             const float* __restrict__ bias, const float* __restrict__ bias2,
             long sBias,
             const float* __restrict__ cs, long sCS,
             const float* __restrict__ shift, long sShift,
             float* __restrict__ psum_out,
             float scale, int M, int N, int K, long sA, long sB, long sC)
{
  A += blockIdx.z * sA;
  B += blockIdx.z * sB;
  if (HAS_BIAS) bias += blockIdx.z * sBias;
  if (HAS_CS || HAS_CSP) cs += blockIdx.z * sCS;
  if (HAS_SHIFT) shift += blockIdx.z * sShift;
  const int bm = blockIdx.y * 128;
  const int bn = blockIdx.x * 128;
  __shared__ __align__(16) u16 smem[128 * 128];   // As=[0,8K), Bs=[8K,16K) u16
  u16* As = smem;
  u16* Bs = smem + 128 * 64;
  __shared__ float psum[4][128];
  const int tid = threadIdx.x;
  const int lane = tid & 63;
  const int wave = tid >> 6;
  const int wm = (wave >> 1) * 64;
  const int wn = (wave & 1) * 64;
  const int lr = lane & 15;          // frag row (A) / col (B,D)
  const int q  = lane >> 4;          // 16B slot quarter within k
  const int sxor = lane & 7;
  const bool gps = (OM == 3) && (bm >= 512);   // g-half of merged kernel
  f32x4 acc[4][4] = {};

  if (HAS_CSP) {
    if (tid < 128) {
      float s = 0.f;
      #pragma unroll
      for (int xx = 0; xx < 8; xx++) s += cs[xx * 4096 + bn + tid];
      psum[0][tid] = 1.0f / s;
    }
    // first __syncthreads in K-loop makes this visible before epilogue use
  }

  const int swz = ((lane & 7) ^ (lane >> 3)) * 8;
  const long grow = 32 * wave + (lane >> 3);
  const u16* Ag = A + ((long)bm + grow) * K + swz;
  const u16* Bg = B + ((long)bn + grow) * K + swz;

  for (int kt = 0; kt < K; kt += 64) {
    __syncthreads();
    #pragma unroll
    for (int i = 0; i < 4; i++) {
      gload16(Ag + (long)(8 * i) * K + kt, &As[(wave * 4 + i) * 512]);
      gload16(Bg + (long)(8 * i) * K + kt, &Bs[(wave * 4 + i) * 512]);
    }
    __syncthreads();
    #pragma unroll
    for (int kk = 0; kk < 2; kk++) {
      short8 av[4], bv[4];
      #pragma unroll
      for (int mi = 0; mi < 4; mi++)
        av[mi] = *(const short8*)&As[(wm + mi * 16 + lr) * 64 +
                                     (((kk << 2) + q) ^ sxor) * 8];
      #pragma unroll
      for (int ni = 0; ni < 4; ni++)
        bv[ni] = *(const short8*)&Bs[(wn + ni * 16 + lr) * 64 +
                                     (((kk << 2) + q) ^ sxor) * 8];
      #pragma unroll
      for (int mi = 0; mi < 4; mi++) {
        #pragma unroll
        for (int ni = 0; ni < 4; ni++)
          acc[mi][ni] = __builtin_amdgcn_mfma_f32_16x16x32_bf16(
              av[mi], bv[ni], acc[mi][ni], 0, 0, 0);
      }
    }
  }

  // epilogue: keep inv (psum[0]) live for HAS_CSP; stage out-tile in smem
  float invc[4];
  if (HAS_CSP) {
    #pragma unroll
    for (int ni = 0; ni < 4; ni++) invc[ni] = psum[0][wn + ni * 16 + lr];
  }
  __syncthreads();   // all waves done with As/Bs ds_reads (and inv loads)
  const int dr = (lane >> 4) * 4;
  const bool trans_out = (OM == 1) || (OM == 3 && !gps);
  float rowsum[4][4];
  float rowsq[4][4];
  if (HAS_EXP || HAS_PSUM2 || gps) {
    #pragma unroll
    for (int mi = 0; mi < 4; mi++)
      #pragma unroll
      for (int r = 0; r < 4; r++) { rowsum[mi][r] = 0.f; rowsq[mi][r] = 0.f; }
  }
  const float* bp = (OM == 3 && gps) ? bias2 - 512 : bias;
  #pragma unroll
  for (int mi = 0; mi < 4; mi++) {
    const int rowl = wm + mi * 16 + dr;      // local row base
    const int rowb = bm + rowl;              // global row base
    float bvs[4] = {0.f, 0.f, 0.f, 0.f};
    float shv[4] = {0.f, 0.f, 0.f, 0.f};
    if (HAS_BIAS) {
      #pragma unroll
      for (int r = 0; r < 4; r++) bvs[r] = bp[rowb + r];
    }
    if (HAS_SHIFT) {
      #pragma unroll
      for (int r = 0; r < 4; r++) shv[r] = shift[rowb + r];
    }
    #pragma unroll
    for (int ni = 0; ni < 4; ni++) {
      const int coll = wn + ni * 16 + lr;    // local col
      const float csv = HAS_CSP ? invc[ni] : (HAS_CS ? cs[bn + coll] : 1.0f);
      float v[4];
      #pragma unroll
      for (int r = 0; r < 4; r++) {
        float t = acc[mi][ni][r] * scale;
        if (HAS_CS || HAS_CSP) t *= csv;
        if (HAS_SHIFT) t -= shv[r];
        if (HAS_BIAS) t += bvs[r];
        if (HAS_EXP) t = expf(t);
        if (HAS_EXP || HAS_PSUM2 || gps) rowsum[mi][r] += t;
        if (HAS_PSUM2) rowsq[mi][r] += t * t;
        v[r] = t;
      }
      if (trans_out) {
        // [col][row] layout, byte-XOR swizzle on bits 4-6
        u16x4 w;
        #pragma unroll
        for (int r = 0; r < 4; r++) w[r] = f2bf(v[r]);
        unsigned bo = (unsigned)((coll * 128 + rowl) * 2) ^ ((coll & 7) << 4);
        *(u16x4*)((char*)smem + bo) = w;
      } else {
        // [row][col] layout, scalar writes (banks spread by col/2: free)
        #pragma unroll
        for (int r = 0; r < 4; r++) smem[(rowl + r) * 128 + coll] = f2bf(v[r]);
      }
    }
  }
  if (HAS_EXP || HAS_PSUM2 || gps) {
    #pragma unroll
    for (int msk = 1; msk < 16; msk <<= 1)
      #pragma unroll
      for (int mi = 0; mi < 4; mi++)
        #pragma unroll
        for (int r = 0; r < 4; r++) {
          rowsum[mi][r] += __shfl_xor(rowsum[mi][r], msk);
          if (HAS_PSUM2) rowsq[mi][r] += __shfl_xor(rowsq[mi][r], msk);
        }
    if ((lane & 15) == 0) {
      #pragma unroll
      for (int mi = 0; mi < 4; mi++)
        #pragma unroll
        for (int r = 0; r < 4; r++) {
          psum[wave & 1][wm + mi * 16 + dr + r] = rowsum[mi][r];
          if (HAS_PSUM2) psum[2 + (wave & 1)][wm + mi * 16 + dr + r] = rowsq[mi][r];
        }
    }
  }
  __syncthreads();
  // coalesced flush: 8 x (ds_read_b128 + global_store_dwordx4) per thread
  if (trans_out) {
    const int Ms = (OM == 3) ? 512 : M;
    u16* C = (u16*)Cv + blockIdx.z * sC;
    #pragma unroll
    for (int i = 0; i < 8; i++) {
      const int chunk = i * 256 + tid;
      const int coll = chunk >> 4, rq = chunk & 15;
      unsigned bo = (unsigned)(coll * 256 + rq * 16) ^ ((coll & 7) << 4);
      uint4 w = *(const uint4*)((const char*)smem + bo);
      *(uint4*)(C + (long)(bn + coll) * Ms + bm + rq * 8) = w;
    }
  } else {
    u16* C = (OM == 3) ? (u16*)Cv2 + blockIdx.z * sC : (u16*)Cv + blockIdx.z * sC;
    const int rbase = (OM == 3) ? bm - 512 : bm;
    #pragma unroll
    for (int i = 0; i < 8; i++) {
      const int chunk = i * 256 + tid;
      const int row = chunk >> 4, cq = chunk & 15;
      uint4 w = *(const uint4*)(smem + row * 128 + cq * 8);
      *(uint4*)(C + (long)(rbase + row) * N + bn + cq * 8) = w;
    }
  }
  if (HAS_EXP || HAS_PSUM2 || gps) {
    if (tid < 128) {
      if (HAS_EXP)
        psum_out[((long)blockIdx.z * gridDim.x + blockIdx.x) * 4096 + bm + tid] =
            psum[0][tid] + psum[1][tid];
      if (HAS_PSUM2) {
        const long blk = ((long)blockIdx.z * gridDim.y + blockIdx.y) * gridDim.x
                         + blockIdx.x;
        psum_out[blk * 256 + tid] = psum[0][tid] + psum[1][tid];
        psum_out[blk * 256 + 128 + tid] = psum[2][tid] + psum[3][tid];
      }
      if (gps)
        psum_out[((long)blockIdx.z * gridDim.x + blockIdx.x) * 512 +
                 (bm - 512) + tid] = psum[0][tid] + psum[1][tid];
    }
  }
}

// ------- gbar[b][d] = (1/1024) * sum_x g_ps[b][x][d] --------------------
__global__ __launch_bounds__(256) void gbar_kernel(const float* __restrict__ g_ps,
                                                   float* __restrict__ gbar) {
  const int idx = blockIdx.x * 256 + threadIdx.x;   // 0..4095 = b*512+d
  const int b = idx >> 9, d = idx & 511;
  const float* p = g_ps + (long)b * 8 * 512 + d;
  float s = 0.f;
  #pragma unroll
  for (int xx = 0; xx < 8; xx++) s += p[(long)xx * 512];
  gbar[idx] = s * (1.0f / 1024.0f);
}

// ------- c0[b][c] = out_b[c] + sum_d out_w_f32[c][d]*gbar[b][d] ----------
__global__ __launch_bounds__(256) void c0_kernel(const float* __restrict__ out_w,
                                                 const float* __restrict__ out_b,
                                                 const float* __restrict__ gbar,
                                                 float* __restrict__ c0) {
  const int idx = blockIdx.x * 4 + (threadIdx.x >> 6);   // 0..8191 = b*1024+c
  const int lane = threadIdx.x & 63;
  const int b = idx >> 10, c = idx & 1023;
  const int d0 = lane * 8;
  float4 w0 = *(const float4*)(out_w + (long)c * DI + d0);
  float4 w1 = *(const float4*)(out_w + (long)c * DI + d0 + 4);
  float4 g0 = *(const float4*)(gbar + (long)b * DI + d0);
  float4 g1 = *(const float4*)(gbar + (long)b * DI + d0 + 4);
  float s = w0.x * g0.x + w0.y * g0.y + w0.z * g0.z + w0.w * g0.w
          + w1.x * g1.x + w1.y * g1.y + w1.z * g1.z + w1.w * g1.w;
  #pragma unroll
  for (int off = 32; off > 0; off >>= 1) s += __shfl_xor(s, off);
  if (lane == 0) c0[idx] = out_b[c] + s;
}

// ------ BN stats from y-GEMM per-block partials + c0 ---------------------
// partial blk layout: blk = ((b*8 + by)*32 + bx), [0..127]=sum, [128..255]=sq
__global__ __launch_bounds__(256) void stats2_kernel(const float* __restrict__ partial,
                                                     const float* __restrict__ c0,
                                                     float* __restrict__ stats) {
  const int co = blockIdx.x * 256 + threadIdx.x;  // 0..1023
  const int by = co >> 7, r = co & 127;
  float sd = 0.f, sd2 = 0.f, sbc = 0.f;
  for (int b = 0; b < 8; b++) {
    float sb = 0.f, qb = 0.f;
    #pragma unroll
    for (int bx = 0; bx < 32; bx++) {
      const long blk = (((long)b * 8 + by) * 32 + bx) * 256;
      sb += partial[blk + r];
      qb += partial[blk + 128 + r];
    }
    sd += sb; sd2 += qb;
    sbc += c0[b * 1024 + co] * sb;
  }
  float sc0 = 0.f, sc02 = 0.f;
  #pragma unroll
  for (int b = 0; b < 8; b++) {
    float c = c0[b * 1024 + co];
    sc0 += c; sc02 += c * c;
  }
  stats[co] = 4096.0f * sc0 + sd;
  stats[1024 + co] = 4096.0f * sc02 + 2.0f * sbc + sd2;
}

// ---------------- BN apply + residual (bf16 dy + c0) ----------------
__global__ __launch_bounds__(256) void final_kernel(const u16* __restrict__ dy,
    const float* __restrict__ x, const float* __restrict__ stats,
    const float* __restrict__ c0,
    const float* __restrict__ bnw, const float* __restrict__ bnb,
    float* __restrict__ out) {
  const int bc = blockIdx.x;
  const int co = bc & 1023;
  const float mean = stats[co] * (1.0f / 32768.0f);
  const float var = stats[1024 + co] * (1.0f / 32768.0f) - mean * mean;
  const float inv = rsqrtf(var + 1e-5f) * bnw[co];
  const float addc = bnb[co] - mean * inv + c0[bc] * inv;
  const long base = (long)bc * 4096;
  const int t = threadIdx.x;
  #pragma unroll
  for (int i = 0; i < 2; i++) {
    const long off = base + (long)(i * 256 + t) * 8;
    uint4 v = *(const uint4*)(dy + off);
    float f[8]; unpack8(v, f);
    const float4 x0 = *(const float4*)(x + off);
    const float4 x1 = *(const float4*)(x + off + 4);
    float4 o0, o1;
    o0.x = f[0] * inv + addc + x0.x;
    o0.y = f[1] * inv + addc + x0.y;
    o0.z = f[2] * inv + addc + x0.z;
    o0.w = f[3] * inv + addc + x0.w;
    o1.x = f[4] * inv + addc + x1.x;
    o1.y = f[5] * inv + addc + x1.y;
    o1.z = f[6] * inv + addc + x1.z;
    o1.w = f[7] * inv + addc + x1.w;
    *(float4*)(out + off) = o0;
    *(float4*)(out + off + 4) = o1;
  }
}

extern "C" void kernel_launch(void* const* d_in, const int* in_sizes, int n_in,
                              void* d_out, int out_size, void* d_ws, size_t ws_size,
                              hipStream_t stream) {
  (void)in_sizes; (void)n_in; (void)out_size; (void)ws_size;
  const float* x       = (const float*)d_in[0];
  const float* theta_w = (const float*)d_in[1];
  const float* theta_b = (const float*)d_in[2];
  const float* phi_w   = (const float*)d_in[3];
  const float* phi_b   = (const float*)d_in[4];
  const float* g_w     = (const float*)d_in[5];
  const float* g_b     = (const float*)d_in[6];
  const float* out_w   = (const float*)d_in[7];
  const float* out_b   = (const float*)d_in[8];
  const float* bn_w    = (const float*)d_in[9];
  const float* bn_b    = (const float*)d_in[10];
  float* out = (float*)d_out;
  char* ws = (char*)d_ws;
  const size_t MB = 1024 * 1024;

  // workspace layout
  u16* xT     = (u16*)(ws + 0 * MB);       // 64MB; later: dy bf16 [0,64MB)
  u16* poolT  = (u16*)(ws + 64 * MB);      // 16MB
  u16* w_th   = (u16*)(ws + 80 * MB);      // 1MB
  u16* w_ph   = (u16*)(ws + 81 * MB);      // 1MB  (w_ph || w_g contiguous)
  u16* w_g    = (u16*)(ws + 82 * MB);      // 1MB
  u16* thetaT = (u16*)(ws + 84 * MB);      // 32MB
  u16* phiT   = (u16*)(ws + 116 * MB);     // 8MB
  u16* g_n    = (u16*)(ws + 124 * MB);     // 8MB
  u16* e      = (u16*)(ws + 132 * MB);     // 64MB (exp(scores))
  u16* tT     = (u16*)(ws + 196 * MB);     // 32MB (delta-t bf16)
  u16* w_out  = (u16*)(ws + 228 * MB);     // 1MB
  float* gbar  = (float*)(ws + 229 * MB);            // 16KB
  float* c0b   = (float*)(ws + 229 * MB + 16384);    // 32KB
  float* stats = (float*)(ws + 229 * MB + 49152);    // 8KB
  float* partial = (float*)(ws + 230 * MB);          // 1MB (8*8*4096 f32)
  float* partial2 = (float*)(ws + 231 * MB);         // 2MB (2048 blk * 256 f32)
  float* g_ps = (float*)(ws + 233 * MB);             // 128KB (8*8*512 f32)
  u16* dy = xT;               // alias: x_T dead after theta GEMM

  // 1. weights -> bf16 (single launch)
  cvt4_kernel<<<2048, 256, 0, stream>>>(theta_w, phi_w, g_w, out_w,
                                        w_th, w_ph, w_g, w_out);
  // 2. x -> x_T bf16 ; 3. pool
  transpose_kernel<<<dim3(64, 16, 8), 256, 0, stream>>>(x, xT);
  pool_kernel<<<4096, 256, 0, stream>>>(xT, poolT);
  // 4. theta -> theta_T [b][4096][512]
  gemm_tn<1, true, false, false, false, false, false>
      <<<dim3(32, 4, 8), 256, 0, stream>>>(
      w_th, xT, thetaT, nullptr, theta_b, nullptr, 0L, nullptr, 0L, nullptr, 0L,
      nullptr, 1.0f, 512, 4096, 1024, 0L, (long)NPIX * CIN, (long)NPIX * DI);
  // 5+6. merged phi+g GEMM: rows<512 -> phiT (trans), rows>=512 -> g_n (plain)
  //      also emits g row-partials -> g_ps
  gemm_tn<3, true, false, false, false, false, false>
      <<<dim3(8, 8, 8), 256, 0, stream>>>(
      w_ph, poolT, phiT, g_n, phi_b, g_b, 0L, nullptr, 0L, nullptr, 0L,
      g_ps, 1.0f, 1024, 1024, 1024, 0L, (long)MPIX * CIN, (long)MPIX * DI);
  // 6b. gbar from partials ; c0
  gbar_kernel<<<16, 256, 0, stream>>>(g_ps, gbar);
  c0_kernel<<<2048, 256, 0, stream>>>(out_w, out_b, gbar, c0b);
  // 7. e[n][m] = exp(theta_T*phi_T^T * scale) + per-block rowsum partials
  gemm_tn<0, false, false, false, true, false, false>
      <<<dim3(8, 32, 8), 256, 0, stream>>>(
      thetaT, phiT, e, nullptr, nullptr, nullptr, 0L, nullptr, 0L, nullptr, 0L,
      partial, 0.044194173824159216f, 4096, 1024, 512,
      (long)NPIX * DI, (long)MPIX * DI, (long)NPIX * MPIX);
  // 8+9. delta-t[d][n] = (g_n * e^T)*inv[n] - gbar[d]; inv computed in-kernel
  gemm_tn<1, false, false, true, false, false, true>
      <<<dim3(32, 4, 8), 256, 0, stream>>>(
      g_n, e, tT, nullptr, nullptr, nullptr, 0L, partial, 32768L, gbar, 512L,
      nullptr, 1.0f, 512, 4096, 1024,
      (long)DI * MPIX, (long)NPIX * MPIX, (long)NPIX * DI);
  // 10. dy[co][n] = out_w * delta-t^T -> dy (aliases xT) + BN partials
  gemm_tn<0, false, false, false, false, true, false>
      <<<dim3(32, 8, 8), 256, 0, stream>>>(
      w_out, tT, dy, nullptr, nullptr, nullptr, 0L, nullptr, 0L, nullptr, 0L,
      partial2, 1.0f, 1024, 4096, 512, 0L, (long)NPIX * DI, (long)1024 * NPIX);
  // 11. BN stats from partials + c0 (deterministic)
  stats2_kernel<<<4, 256, 0, stream>>>(partial2, c0b, stats);
  // 12. BN apply + residual
  final_kernel<<<8192, 256, 0, stream>>>(dy, x, stats, c0b, bn_w, bn_b, out);
}

// Round 9
// 356.014 us; speedup vs baseline: 1.0883x; 1.0257x over previous
//
#include <hip/hip_runtime.h>
#include <cstdint>

typedef unsigned short u16;
typedef __attribute__((ext_vector_type(4))) unsigned short u16x4;
typedef __attribute__((ext_vector_type(8))) short short8;
typedef __attribute__((ext_vector_type(4))) float f32x4;

#define DI 512
#define CIN 1024
#define NPIX 4096   // 64*64
#define MPIX 1024   // 32*32

__device__ __forceinline__ float bf2f(u16 u) {
  union { unsigned int i; float f; } v; v.i = ((unsigned int)u) << 16; return v.f;
}
__device__ __forceinline__ u16 f2bf(float f) {
  union { float f; unsigned int i; } v; v.f = f;
  unsigned int r = v.i + 0x7fffu + ((v.i >> 16) & 1u);
  return (u16)(r >> 16);
}
__device__ __forceinline__ void unpack8(uint4 v, float* f) {
  union { unsigned int i; float f; } u;
  u.i = v.x << 16;          f[0] = u.f;
  u.i = v.x & 0xffff0000u;  f[1] = u.f;
  u.i = v.y << 16;          f[2] = u.f;
  u.i = v.y & 0xffff0000u;  f[3] = u.f;
  u.i = v.z << 16;          f[4] = u.f;
  u.i = v.z & 0xffff0000u;  f[5] = u.f;
  u.i = v.w << 16;          f[6] = u.f;
  u.i = v.w & 0xffff0000u;  f[7] = u.f;
}

// async global->LDS, 16B per lane, wave-uniform LDS base + lane*16
__device__ __forceinline__ void gload16(const u16* g, u16* l) {
  __builtin_amdgcn_global_load_lds(
      (const __attribute__((address_space(1))) void*)g,
      (__attribute__((address_space(3))) void*)l, 16, 0, 0);
}

// ---------------- f32 -> bf16 convert (4 weight tensors in one launch) ----
__global__ __launch_bounds__(256) void cvt4_kernel(
    const float* __restrict__ s0, const float* __restrict__ s1,
    const float* __restrict__ s2, const float* __restrict__ s3,
    u16* __restrict__ d0, u16* __restrict__ d1,
    u16* __restrict__ d2, u16* __restrict__ d3) {
  int i = blockIdx.x * 256 + threadIdx.x;     // 0 .. 4*131072
  int sel = i >> 17;
  int j = i & 131071;
  const float* src = sel == 0 ? s0 : sel == 1 ? s1 : sel == 2 ? s2 : s3;
  u16* dst = sel == 0 ? d0 : sel == 1 ? d1 : sel == 2 ? d2 : d3;
  float4 v = *(const float4*)(src + (long)j * 4);
  u16x4 w;
  w[0] = f2bf(v.x); w[1] = f2bf(v.y); w[2] = f2bf(v.z); w[3] = f2bf(v.w);
  *(u16x4*)(dst + (long)j * 4) = w;
}

// ------- x [b][c][n] f32 -> x_T [b][n][c] bf16 + fused 2x2 maxpool -------
// Block: 128 n (= 2 image rows) x 64 c. Pool phase: j=t&31 (pooled col),
// g=t>>5 (c-octet) -> LDS reads are 2-way-aliased dwords (conflict-free).
__global__ __launch_bounds__(256) void transpose_pool_kernel(
    const float* __restrict__ x, u16* __restrict__ xT, u16* __restrict__ poolT) {
  __shared__ u16 tile[64][136];
  const int b = blockIdx.z;
  const int n0 = blockIdx.x * 128, c0 = blockIdx.y * 64;
  const float* xb = x + (long)b * CIN * NPIX;
  u16* xTb = xT + (long)b * NPIX * CIN;
  const int t = threadIdx.x;
  // phase 1: load 64c x 128n f32, convert, store tile
  const int tc = t >> 5, tn = (t & 31) * 4;
  #pragma unroll
  for (int i = 0; i < 8; i++) {
    int c = tc + i * 8;
    float4 v = *(const float4*)(xb + (long)(c0 + c) * NPIX + n0 + tn);
    u16x4 w;
    w[0] = f2bf(v.x); w[1] = f2bf(v.y); w[2] = f2bf(v.z); w[3] = f2bf(v.w);
    *(u16x4*)&tile[c][tn] = w;
  }
  __syncthreads();
  // phase 2: transposed write to xT
  const int tn2 = t >> 4, tc2 = (t & 15) * 4;
  #pragma unroll
  for (int i = 0; i < 8; i++) {
    int n = tn2 + i * 16;
    u16x4 w;
    w[0] = tile[tc2 + 0][n];
    w[1] = tile[tc2 + 1][n];
    w[2] = tile[tc2 + 2][n];
    w[3] = tile[tc2 + 3][n];
    *(u16x4*)(xTb + (long)(n0 + n) * CIN + c0 + tc2) = w;
  }
  // phase 3: 2x2 maxpool from tile (rows 2bx,2bx+1 -> pooled row bx)
  const int j = t & 31, g = t >> 5;
  u16 r[8] __attribute__((aligned(16)));
  #pragma unroll
  for (int k = 0; k < 8; k++) {
    const int c = g * 8 + k;
    const unsigned d0 = *(const unsigned*)&tile[c][2 * j];
    const unsigned d1 = *(const unsigned*)&tile[c][64 + 2 * j];
    float m0 = fmaxf(bf2f((u16)(d0 & 0xffffu)), bf2f((u16)(d0 >> 16)));
    float m1 = fmaxf(bf2f((u16)(d1 & 0xffffu)), bf2f((u16)(d1 >> 16)));
    r[k] = f2bf(fmaxf(m0, m1));
  }
  *(uint4*)(poolT + ((long)b * MPIX + blockIdx.x * 32 + j) * CIN + c0 + g * 8) =
      *(uint4*)r;
}

// ---------------- GEMM: C[M][N] = A[M][K] * B[N][K]^T ----
// global_load_lds staging, linear LDS [128][64] bf16, XOR-swizzled 16B slots.
// OM: 0 = bf16 plain [M][N], 1 = bf16 transposed [N][M],
//     3 = merged: rows<512 -> transposed (stride 512) to Cv,
//                 rows>=512 -> plain to Cv2 (bias2), g row-partials to psum_out.
// HAS_CSP: col-scale = 1/sum_x cs[x*4096+col] (computed in prologue via LDS).
// HAS_EXP: v = exp(acc*scale); per-block row-sums -> psum_out[(z*gX+x)*4096+row].
// HAS_PSUM2: per-block row (sum,sumsq) -> psum_out[blk*256 + {row,128+row}].
template<int OM, bool HAS_BIAS, bool HAS_CS, bool HAS_SHIFT, bool HAS_EXP,
         bool HAS_PSUM2, bool HAS_CSP>
__global__ __launch_bounds__(256)
void gemm_tn(const u16* __restrict__ A, const u16* __restrict__ B,
             void* __restrict__ Cv, void* __restrict__ Cv2,
             const float* __restrict__ bias, const float* __restrict__ bias2,
             long sBias,
             const float* __restrict__ cs, long sCS,
             const float* __restrict__ shift, long sShift,
             float* __restrict__ psum_out,
             float scale, int M, int N, int K, long sA, long sB, long sC)
{
  A += blockIdx.z * sA;
  B += blockIdx.z * sB;
  if (HAS_BIAS) bias += blockIdx.z * sBias;
  if (HAS_CS || HAS_CSP) cs += blockIdx.z * sCS;
  if (HAS_SHIFT) shift += blockIdx.z * sShift;
  const int bm = blockIdx.y * 128;
  const int bn = blockIdx.x * 128;
  __shared__ __align__(16) u16 smem[128 * 128];   // As=[0,8K), Bs=[8K,16K) u16
  u16* As = smem;
  u16* Bs = smem + 128 * 64;
  __shared__ float psum[4][128];
  const int tid = threadIdx.x;
  const int lane = tid & 63;
  const int wave = tid >> 6;
  const int wm = (wave >> 1) * 64;
  const int wn = (wave & 1) * 64;
  const int lr = lane & 15;          // frag row (A) / col (B,D)
  const int q  = lane >> 4;          // 16B slot quarter within k
  const int sxor = lane & 7;
  const bool gps = (OM == 3) && (bm >= 512);   // g-half of merged kernel
  f32x4 acc[4][4] = {};

  if (HAS_CSP) {
    if (tid < 128) {
      float s = 0.f;
      #pragma unroll
      for (int xx = 0; xx < 8; xx++) s += cs[xx * 4096 + bn + tid];
      psum[0][tid] = 1.0f / s;
    }
    // first __syncthreads in K-loop makes this visible before epilogue use
  }

  const int swz = ((lane & 7) ^ (lane >> 3)) * 8;
  const long grow = 32 * wave + (lane >> 3);
  const u16* Ag = A + ((long)bm + grow) * K + swz;
  const u16* Bg = B + ((long)bn + grow) * K + swz;

  for (int kt = 0; kt < K; kt += 64) {
    __syncthreads();
    #pragma unroll
    for (int i = 0; i < 4; i++) {
      gload16(Ag + (long)(8 * i) * K + kt, &As[(wave * 4 + i) * 512]);
      gload16(Bg + (long)(8 * i) * K + kt, &Bs[(wave * 4 + i) * 512]);
    }
    __syncthreads();
    #pragma unroll
    for (int kk = 0; kk < 2; kk++) {
      short8 av[4], bv[4];
      #pragma unroll
      for (int mi = 0; mi < 4; mi++)
        av[mi] = *(const short8*)&As[(wm + mi * 16 + lr) * 64 +
                                     (((kk << 2) + q) ^ sxor) * 8];
      #pragma unroll
      for (int ni = 0; ni < 4; ni++)
        bv[ni] = *(const short8*)&Bs[(wn + ni * 16 + lr) * 64 +
                                     (((kk << 2) + q) ^ sxor) * 8];
      #pragma unroll
      for (int mi = 0; mi < 4; mi++) {
        #pragma unroll
        for (int ni = 0; ni < 4; ni++)
          acc[mi][ni] = __builtin_amdgcn_mfma_f32_16x16x32_bf16(
              av[mi], bv[ni], acc[mi][ni], 0, 0, 0);
      }
    }
  }

  // epilogue: keep inv (psum[0]) live for HAS_CSP; stage out-tile in smem
  float invc[4];
  if (HAS_CSP) {
    #pragma unroll
    for (int ni = 0; ni < 4; ni++) invc[ni] = psum[0][wn + ni * 16 + lr];
  }
  __syncthreads();   // all waves done with As/Bs ds_reads (and inv loads)
  const int dr = (lane >> 4) * 4;
  const bool trans_out = (OM == 1) || (OM == 3 && !gps);
  float rowsum[4][4];
  float rowsq[4][4];
  if (HAS_EXP || HAS_PSUM2 || gps) {
    #pragma unroll
    for (int mi = 0; mi < 4; mi++)
      #pragma unroll
      for (int r = 0; r < 4; r++) { rowsum[mi][r] = 0.f; rowsq[mi][r] = 0.f; }
  }
  const float* bp = (OM == 3 && gps) ? bias2 - 512 : bias;
  #pragma unroll
  for (int mi = 0; mi < 4; mi++) {
    const int rowl = wm + mi * 16 + dr;      // local row base
    const int rowb = bm + rowl;              // global row base
    float bvs[4] = {0.f, 0.f, 0.f, 0.f};
    float shv[4] = {0.f, 0.f, 0.f, 0.f};
    if (HAS_BIAS) {
      #pragma unroll
      for (int r = 0; r < 4; r++) bvs[r] = bp[rowb + r];
    }
    if (HAS_SHIFT) {
      #pragma unroll
      for (int r = 0; r < 4; r++) shv[r] = shift[rowb + r];
    }
    #pragma unroll
    for (int ni = 0; ni < 4; ni++) {
      const int coll = wn + ni * 16 + lr;    // local col
      const float csv = HAS_CSP ? invc[ni] : (HAS_CS ? cs[bn + coll] : 1.0f);
      float v[4];
      #pragma unroll
      for (int r = 0; r < 4; r++) {
        float t = acc[mi][ni][r] * scale;
        if (HAS_CS || HAS_CSP) t *= csv;
        if (HAS_SHIFT) t -= shv[r];
        if (HAS_BIAS) t += bvs[r];
        if (HAS_EXP) t = expf(t);
        if (HAS_EXP || HAS_PSUM2 || gps) rowsum[mi][r] += t;
        if (HAS_PSUM2) rowsq[mi][r] += t * t;
        v[r] = t;
      }
      if (trans_out) {
        // [col][row] layout, byte-XOR swizzle on bits 4-6
        u16x4 w;
        #pragma unroll
        for (int r = 0; r < 4; r++) w[r] = f2bf(v[r]);
        unsigned bo = (unsigned)((coll * 128 + rowl) * 2) ^ ((coll & 7) << 4);
        *(u16x4*)((char*)smem + bo) = w;
      } else {
        // [row][col] layout, scalar writes (banks spread by col/2: free)
        #pragma unroll
        for (int r = 0; r < 4; r++) smem[(rowl + r) * 128 + coll] = f2bf(v[r]);
      }
    }
  }
  if (HAS_EXP || HAS_PSUM2 || gps) {
    #pragma unroll
    for (int msk = 1; msk < 16; msk <<= 1)
      #pragma unroll
      for (int mi = 0; mi < 4; mi++)
        #pragma unroll
        for (int r = 0; r < 4; r++) {
          rowsum[mi][r] += __shfl_xor(rowsum[mi][r], msk);
          if (HAS_PSUM2) rowsq[mi][r] += __shfl_xor(rowsq[mi][r], msk);
        }
    if ((lane & 15) == 0) {
      #pragma unroll
      for (int mi = 0; mi < 4; mi++)
        #pragma unroll
        for (int r = 0; r < 4; r++) {
          psum[wave & 1][wm + mi * 16 + dr + r] = rowsum[mi][r];
          if (HAS_PSUM2) psum[2 + (wave & 1)][wm + mi * 16 + dr + r] = rowsq[mi][r];
        }
    }
  }
  __syncthreads();
  // coalesced flush: 8 x (ds_read_b128 + global_store_dwordx4) per thread
  if (trans_out) {
    const int Ms = (OM == 3) ? 512 : M;
    u16* C = (u16*)Cv + blockIdx.z * sC;
    #pragma unroll
    for (int i = 0; i < 8; i++) {
      const int chunk = i * 256 + tid;
      const int coll = chunk >> 4, rq = chunk & 15;
      unsigned bo = (unsigned)(coll * 256 + rq * 16) ^ ((coll & 7) << 4);
      uint4 w = *(const uint4*)((const char*)smem + bo);
      *(uint4*)(C + (long)(bn + coll) * Ms + bm + rq * 8) = w;
    }
  } else {
    u16* C = (OM == 3) ? (u16*)Cv2 + blockIdx.z * sC : (u16*)Cv + blockIdx.z * sC;
    const int rbase = (OM == 3) ? bm - 512 : bm;
    #pragma unroll
    for (int i = 0; i < 8; i++) {
      const int chunk = i * 256 + tid;
      const int row = chunk >> 4, cq = chunk & 15;
      uint4 w = *(const uint4*)(smem + row * 128 + cq * 8);
      *(uint4*)(C + (long)(rbase + row) * N + bn + cq * 8) = w;
    }
  }
  if (HAS_EXP || HAS_PSUM2 || gps) {
    if (tid < 128) {
      if (HAS_EXP)
        psum_out[((long)blockIdx.z * gridDim.x + blockIdx.x) * 4096 + bm + tid] =
            psum[0][tid] + psum[1][tid];
      if (HAS_PSUM2) {
        const long blk = ((long)blockIdx.z * gridDim.y + blockIdx.y) * gridDim.x
                         + blockIdx.x;
        psum_out[blk * 256 + tid] = psum[0][tid] + psum[1][tid];
        psum_out[blk * 256 + 128 + tid] = psum[2][tid] + psum[3][tid];
      }
      if (gps)
        psum_out[((long)blockIdx.z * gridDim.x + blockIdx.x) * 512 +
                 (bm - 512) + tid] = psum[0][tid] + psum[1][tid];
    }
  }
}

// ------- gbar[b][d] = (1/1024) * sum_x g_ps[b][x][d] --------------------
__global__ __launch_bounds__(256) void gbar_kernel(const float* __restrict__ g_ps,
                                                   float* __restrict__ gbar) {
  const int idx = blockIdx.x * 256 + threadIdx.x;   // 0..4095 = b*512+d
  const int b = idx >> 9, d = idx & 511;
  const float* p = g_ps + (long)b * 8 * 512 + d;
  float s = 0.f;
  #pragma unroll
  for (int xx = 0; xx < 8; xx++) s += p[(long)xx * 512];
  gbar[idx] = s * (1.0f / 1024.0f);
}

// ------- c0[b][c] = out_b[c] + sum_d out_w_f32[c][d]*gbar[b][d] ----------
__global__ __launch_bounds__(256) void c0_kernel(const float* __restrict__ out_w,
                                                 const float* __restrict__ out_b,
                                                 const float* __restrict__ gbar,
                                                 float* __restrict__ c0) {
  const int idx = blockIdx.x * 4 + (threadIdx.x >> 6);   // 0..8191 = b*1024+c
  const int lane = threadIdx.x & 63;
  const int b = idx >> 10, c = idx & 1023;
  const int d0 = lane * 8;
  float4 w0 = *(const float4*)(out_w + (long)c * DI + d0);
  float4 w1 = *(const float4*)(out_w + (long)c * DI + d0 + 4);
  float4 g0 = *(const float4*)(gbar + (long)b * DI + d0);
  float4 g1 = *(const float4*)(gbar + (long)b * DI + d0 + 4);
  float s = w0.x * g0.x + w0.y * g0.y + w0.z * g0.z + w0.w * g0.w
          + w1.x * g1.x + w1.y * g1.y + w1.z * g1.z + w1.w * g1.w;
  #pragma unroll
  for (int off = 32; off > 0; off >>= 1) s += __shfl_xor(s, off);
  if (lane == 0) c0[idx] = out_b[c] + s;
}

// ------ BN stats from y-GEMM per-block partials + c0 ---------------------
// partial blk layout: blk = ((b*8 + by)*32 + bx), [0..127]=sum, [128..255]=sq
__global__ __launch_bounds__(256) void stats2_kernel(const float* __restrict__ partial,
                                                     const float* __restrict__ c0,
                                                     float* __restrict__ stats) {
  const int co = blockIdx.x * 256 + threadIdx.x;  // 0..1023
  const int by = co >> 7, r = co & 127;
  float sd = 0.f, sd2 = 0.f, sbc = 0.f;
  for (int b = 0; b < 8; b++) {
    float sb = 0.f, qb = 0.f;
    #pragma unroll
    for (int bx = 0; bx < 32; bx++) {
      const long blk = (((long)b * 8 + by) * 32 + bx) * 256;
      sb += partial[blk + r];
      qb += partial[blk + 128 + r];
    }
    sd += sb; sd2 += qb;
    sbc += c0[b * 1024 + co] * sb;
  }
  float sc0 = 0.f, sc02 = 0.f;
  #pragma unroll
  for (int b = 0; b < 8; b++) {
    float c = c0[b * 1024 + co];
    sc0 += c; sc02 += c * c;
  }
  stats[co] = 4096.0f * sc0 + sd;
  stats[1024 + co] = 4096.0f * sc02 + 2.0f * sbc + sd2;
}

// ---------------- BN apply + residual (bf16 dy + c0) ----------------
__global__ __launch_bounds__(256) void final_kernel(const u16* __restrict__ dy,
    const float* __restrict__ x, const float* __restrict__ stats,
    const float* __restrict__ c0,
    const float* __restrict__ bnw, const float* __restrict__ bnb,
    float* __restrict__ out) {
  const int bc = blockIdx.x;
  const int co = bc & 1023;
  const float mean = stats[co] * (1.0f / 32768.0f);
  const float var = stats[1024 + co] * (1.0f / 32768.0f) - mean * mean;
  const float inv = rsqrtf(var + 1e-5f) * bnw[co];
  const float addc = bnb[co] - mean * inv + c0[bc] * inv;
  const long base = (long)bc * 4096;
  const int t = threadIdx.x;
  #pragma unroll
  for (int i = 0; i < 2; i++) {
    const long off = base + (long)(i * 256 + t) * 8;
    uint4 v = *(const uint4*)(dy + off);
    float f[8]; unpack8(v, f);
    const float4 x0 = *(const float4*)(x + off);
    const float4 x1 = *(const float4*)(x + off + 4);
    float4 o0, o1;
    o0.x = f[0] * inv + addc + x0.x;
    o0.y = f[1] * inv + addc + x0.y;
    o0.z = f[2] * inv + addc + x0.z;
    o0.w = f[3] * inv + addc + x0.w;
    o1.x = f[4] * inv + addc + x1.x;
    o1.y = f[5] * inv + addc + x1.y;
    o1.z = f[6] * inv + addc + x1.z;
    o1.w = f[7] * inv + addc + x1.w;
    *(float4*)(out + off) = o0;
    *(float4*)(out + off + 4) = o1;
  }
}

extern "C" void kernel_launch(void* const* d_in, const int* in_sizes, int n_in,
                              void* d_out, int out_size, void* d_ws, size_t ws_size,
                              hipStream_t stream) {
  (void)in_sizes; (void)n_in; (void)out_size; (void)ws_size;
  const float* x       = (const float*)d_in[0];
  const float* theta_w = (const float*)d_in[1];
  const float* theta_b = (const float*)d_in[2];
  const float* phi_w   = (const float*)d_in[3];
  const float* phi_b   = (const float*)d_in[4];
  const float* g_w     = (const float*)d_in[5];
  const float* g_b     = (const float*)d_in[6];
  const float* out_w   = (const float*)d_in[7];
  const float* out_b   = (const float*)d_in[8];
  const float* bn_w    = (const float*)d_in[9];
  const float* bn_b    = (const float*)d_in[10];
  float* out = (float*)d_out;
  char* ws = (char*)d_ws;
  const size_t MB = 1024 * 1024;

  // workspace layout
  u16* xT     = (u16*)(ws + 0 * MB);       // 64MB; later: dy bf16 [0,64MB)
  u16* poolT  = (u16*)(ws + 64 * MB);      // 16MB
  u16* w_th   = (u16*)(ws + 80 * MB);      // 1MB
  u16* w_ph   = (u16*)(ws + 81 * MB);      // 1MB  (w_ph || w_g contiguous)
  u16* w_g    = (u16*)(ws + 82 * MB);      // 1MB
  u16* thetaT = (u16*)(ws + 84 * MB);      // 32MB
  u16* phiT   = (u16*)(ws + 116 * MB);     // 8MB
  u16* g_n    = (u16*)(ws + 124 * MB);     // 8MB
  u16* e      = (u16*)(ws + 132 * MB);     // 64MB (exp(scores))
  u16* tT     = (u16*)(ws + 196 * MB);     // 32MB (delta-t bf16)
  u16* w_out  = (u16*)(ws + 228 * MB);     // 1MB
  float* gbar  = (float*)(ws + 229 * MB);            // 16KB
  float* c0b   = (float*)(ws + 229 * MB + 16384);    // 32KB
  float* stats = (float*)(ws + 229 * MB + 49152);    // 8KB
  float* partial = (float*)(ws + 230 * MB);          // 1MB (8*8*4096 f32)
  float* partial2 = (float*)(ws + 231 * MB);         // 2MB (2048 blk * 256 f32)
  float* g_ps = (float*)(ws + 233 * MB);             // 128KB (8*8*512 f32)
  u16* dy = xT;               // alias: x_T dead after theta GEMM

  // 1. weights -> bf16 (single launch)
  cvt4_kernel<<<2048, 256, 0, stream>>>(theta_w, phi_w, g_w, out_w,
                                        w_th, w_ph, w_g, w_out);
  // 2. x -> x_T bf16 with fused 2x2 maxpool (conflict-free pool phase)
  transpose_pool_kernel<<<dim3(32, 16, 8), 256, 0, stream>>>(x, xT, poolT);
  // 4. theta -> theta_T [b][4096][512]
  gemm_tn<1, true, false, false, false, false, false>
      <<<dim3(32, 4, 8), 256, 0, stream>>>(
      w_th, xT, thetaT, nullptr, theta_b, nullptr, 0L, nullptr, 0L, nullptr, 0L,
      nullptr, 1.0f, 512, 4096, 1024, 0L, (long)NPIX * CIN, (long)NPIX * DI);
  // 5+6. merged phi+g GEMM: rows<512 -> phiT (trans), rows>=512 -> g_n (plain)
  //      also emits g row-partials -> g_ps
  gemm_tn<3, true, false, false, false, false, false>
      <<<dim3(8, 8, 8), 256, 0, stream>>>(
      w_ph, poolT, phiT, g_n, phi_b, g_b, 0L, nullptr, 0L, nullptr, 0L,
      g_ps, 1.0f, 1024, 1024, 1024, 0L, (long)MPIX * CIN, (long)MPIX * DI);
  // 6b. gbar from partials ; c0
  gbar_kernel<<<16, 256, 0, stream>>>(g_ps, gbar);
  c0_kernel<<<2048, 256, 0, stream>>>(out_w, out_b, gbar, c0b);
  // 7. e[n][m] = exp(theta_T*phi_T^T * scale) + per-block rowsum partials
  gemm_tn<0, false, false, false, true, false, false>
      <<<dim3(8, 32, 8), 256, 0, stream>>>(
      thetaT, phiT, e, nullptr, nullptr, nullptr, 0L, nullptr, 0L, nullptr, 0L,
      partial, 0.044194173824159216f, 4096, 1024, 512,
      (long)NPIX * DI, (long)MPIX * DI, (long)NPIX * MPIX);
  // 8+9. delta-t[d][n] = (g_n * e^T)*inv[n] - gbar[d]; inv computed in-kernel
  gemm_tn<1, false, false, true, false, false, true>
      <<<dim3(32, 4, 8), 256, 0, stream>>>(
      g_n, e, tT, nullptr, nullptr, nullptr, 0L, partial, 32768L, gbar, 512L,
      nullptr, 1.0f, 512, 4096, 1024,
      (long)DI * MPIX, (long)NPIX * MPIX, (long)NPIX * DI);
  // 10. dy[co][n] = out_w * delta-t^T -> dy (aliases xT) + BN partials
  gemm_tn<0, false, false, false, false, true, false>
      <<<dim3(32, 8, 8), 256, 0, stream>>>(
      w_out, tT, dy, nullptr, nullptr, nullptr, 0L, nullptr, 0L, nullptr, 0L,
      partial2, 1.0f, 1024, 4096, 512, 0L, (long)NPIX * DI, (long)1024 * NPIX);
  // 11. BN stats from partials + c0 (deterministic)
  stats2_kernel<<<4, 256, 0, stream>>>(partial2, c0b, stats);
  // 12. BN apply + residual
  final_kernel<<<8192, 256, 0, stream>>>(dy, x, stats, c0b, bn_w, bn_b, out);
}

// Round 10
// 343.786 us; speedup vs baseline: 1.1270x; 1.0356x over previous
//
#include <hip/hip_runtime.h>
#include <cstdint>

typedef unsigned short u16;
typedef __attribute__((ext_vector_type(4))) unsigned short u16x4;
typedef __attribute__((ext_vector_type(8))) short short8;
typedef __attribute__((ext_vector_type(4))) float f32x4;

#define DI 512
#define CIN 1024
#define NPIX 4096   // 64*64
#define MPIX 1024   // 32*32

__device__ __forceinline__ float bf2f(u16 u) {
  union { unsigned int i; float f; } v; v.i = ((unsigned int)u) << 16; return v.f;
}
__device__ __forceinline__ u16 f2bf(float f) {
  union { float f; unsigned int i; } v; v.f = f;
  unsigned int r = v.i + 0x7fffu + ((v.i >> 16) & 1u);
  return (u16)(r >> 16);
}
__device__ __forceinline__ void unpack8(uint4 v, float* f) {
  union { unsigned int i; float f; } u;
  u.i = v.x << 16;          f[0] = u.f;
  u.i = v.x & 0xffff0000u;  f[1] = u.f;
  u.i = v.y << 16;          f[2] = u.f;
  u.i = v.y & 0xffff0000u;  f[3] = u.f;
  u.i = v.z << 16;          f[4] = u.f;
  u.i = v.z & 0xffff0000u;  f[5] = u.f;
  u.i = v.w << 16;          f[6] = u.f;
  u.i = v.w & 0xffff0000u;  f[7] = u.f;
}

// async global->LDS, 16B per lane, wave-uniform LDS base + lane*16
__device__ __forceinline__ void gload16(const u16* g, u16* l) {
  __builtin_amdgcn_global_load_lds(
      (const __attribute__((address_space(1))) void*)g,
      (__attribute__((address_space(3))) void*)l, 16, 0, 0);
}

// ---------------- f32 -> bf16 convert (4 weight tensors in one launch) ----
__global__ __launch_bounds__(256) void cvt4_kernel(
    const float* __restrict__ s0, const float* __restrict__ s1,
    const float* __restrict__ s2, const float* __restrict__ s3,
    u16* __restrict__ d0, u16* __restrict__ d1,
    u16* __restrict__ d2, u16* __restrict__ d3) {
  int i = blockIdx.x * 256 + threadIdx.x;     // 0 .. 4*131072
  int sel = i >> 17;
  int j = i & 131071;
  const float* src = sel == 0 ? s0 : sel == 1 ? s1 : sel == 2 ? s2 : s3;
  u16* dst = sel == 0 ? d0 : sel == 1 ? d1 : sel == 2 ? d2 : d3;
  float4 v = *(const float4*)(src + (long)j * 4);
  u16x4 w;
  w[0] = f2bf(v.x); w[1] = f2bf(v.y); w[2] = f2bf(v.z); w[3] = f2bf(v.w);
  *(u16x4*)(dst + (long)j * 4) = w;
}

// ------- x [b][c][n] f32 -> x_T [b][n][c] bf16 + fused 2x2 maxpool -------
__global__ __launch_bounds__(256) void transpose_pool_kernel(
    const float* __restrict__ x, u16* __restrict__ xT, u16* __restrict__ poolT) {
  __shared__ u16 tile[64][136];
  const int b = blockIdx.z;
  const int n0 = blockIdx.x * 128, c0 = blockIdx.y * 64;
  const float* xb = x + (long)b * CIN * NPIX;
  u16* xTb = xT + (long)b * NPIX * CIN;
  const int t = threadIdx.x;
  const int tc = t >> 5, tn = (t & 31) * 4;
  #pragma unroll
  for (int i = 0; i < 8; i++) {
    int c = tc + i * 8;
    float4 v = *(const float4*)(xb + (long)(c0 + c) * NPIX + n0 + tn);
    u16x4 w;
    w[0] = f2bf(v.x); w[1] = f2bf(v.y); w[2] = f2bf(v.z); w[3] = f2bf(v.w);
    *(u16x4*)&tile[c][tn] = w;
  }
  __syncthreads();
  const int tn2 = t >> 4, tc2 = (t & 15) * 4;
  #pragma unroll
  for (int i = 0; i < 8; i++) {
    int n = tn2 + i * 16;
    u16x4 w;
    w[0] = tile[tc2 + 0][n];
    w[1] = tile[tc2 + 1][n];
    w[2] = tile[tc2 + 2][n];
    w[3] = tile[tc2 + 3][n];
    *(u16x4*)(xTb + (long)(n0 + n) * CIN + c0 + tc2) = w;
  }
  const int j = t & 31, g = t >> 5;
  u16 r[8] __attribute__((aligned(16)));
  #pragma unroll
  for (int k = 0; k < 8; k++) {
    const int c = g * 8 + k;
    const unsigned d0 = *(const unsigned*)&tile[c][2 * j];
    const unsigned d1 = *(const unsigned*)&tile[c][64 + 2 * j];
    float m0 = fmaxf(bf2f((u16)(d0 & 0xffffu)), bf2f((u16)(d0 >> 16)));
    float m1 = fmaxf(bf2f((u16)(d1 & 0xffffu)), bf2f((u16)(d1 >> 16)));
    r[k] = f2bf(fmaxf(m0, m1));
  }
  *(uint4*)(poolT + ((long)b * MPIX + blockIdx.x * 32 + j) * CIN + c0 + g * 8) =
      *(uint4*)r;
}

// =============== 256x256-tile GEMM, 8 waves, dbuf + counted vmcnt ========
// C[M][N] = A[M][K]*B[N][K]^T. OM: 0 = bf16 [M][N], 1 = bf16 [N][M].
// K-loop: 2 LDS slots (64KB each: A 32KB | B 32KB); per tile t:
//   barA (slot s^1 reads done) -> stage t+1 into s^1 -> vmcnt(8) (stage t
//   drained; t+1's 8 loads stay in flight) -> barB -> ds_read+MFMA slot s.
// HAS_EXP: v=exp(v); row-sums -> psum_out[(z*gridX+x)*4096 + bm+tid]
// HAS_PSUM2: row (sum,sq) -> psum_out[blk*512 + {tid,256+tid}]
// HAS_CSP: col-scale = 1/sum_{xx<4} cs[xx*4096+col]
template<int OM, bool HAS_BIAS, bool HAS_SHIFT, bool HAS_EXP, bool HAS_PSUM2,
         bool HAS_CSP>
__global__ __launch_bounds__(512, 2)
void gemm256(const u16* __restrict__ A, const u16* __restrict__ B,
             void* __restrict__ Cv,
             const float* __restrict__ bias, long sBias,
             const float* __restrict__ cs, long sCS,
             const float* __restrict__ shift, long sShift,
             float* __restrict__ psum_out,
             float scale, int M, int N, int K, long sA, long sB, long sC)
{
  A += blockIdx.z * sA;
  B += blockIdx.z * sB;
  if (HAS_BIAS) bias += blockIdx.z * sBias;
  if (HAS_CSP) cs += blockIdx.z * sCS;
  if (HAS_SHIFT) shift += blockIdx.z * sShift;
  const int bm = blockIdx.y * 256, bn = blockIdx.x * 256;
  __shared__ __align__(16) u16 smem[65536];   // 2 slots x (A 16384 | B 16384)
  __shared__ float psum[4][256];
  __shared__ float psumq[4][256];
  __shared__ float invs[256];
  const int tid = threadIdx.x;
  const int lane = tid & 63, wave = tid >> 6;
  const int wr = wave >> 2, wc = wave & 3;       // 2M x 4N waves
  const int lr = lane & 15, q = lane >> 4, sx = lane & 7;
  f32x4 acc[8][4] = {};

  if (HAS_CSP && tid < 256) {
    float ssum = 0.f;
    #pragma unroll
    for (int xx = 0; xx < 4; xx++) ssum += cs[xx * 4096 + bn + tid];
    invs[tid] = 1.0f / ssum;
  }

  const int swz = ((lane & 7) ^ (lane >> 3)) * 8;
  const long grow = 32 * wave + (lane >> 3);
  const u16* Ag = A + ((long)bm + grow) * K + swz;
  const u16* Bg = B + ((long)bn + grow) * K + swz;
  const int niter = K >> 6;

  // prologue: stage tile 0 -> slot 0
  #pragma unroll
  for (int i = 0; i < 4; i++) {
    gload16(Ag + (long)(8 * i) * K, &smem[(32 * wave + 8 * i) * 64]);
    gload16(Bg + (long)(8 * i) * K, &smem[16384 + (32 * wave + 8 * i) * 64]);
  }

  for (int t = 0; t < niter; ++t) {
    const int s = t & 1;
    __builtin_amdgcn_s_barrier();            // all waves done reading slot s^1
    __builtin_amdgcn_sched_barrier(0);
    if (t + 1 < niter) {
      const long kofs = (long)(t + 1) * 64;
      const int db = (s ^ 1) * 32768;
      #pragma unroll
      for (int i = 0; i < 4; i++) {
        gload16(Ag + (long)(8 * i) * K + kofs, &smem[db + (32 * wave + 8 * i) * 64]);
        gload16(Bg + (long)(8 * i) * K + kofs,
                &smem[db + 16384 + (32 * wave + 8 * i) * 64]);
      }
      asm volatile("s_waitcnt vmcnt(8)" ::: "memory");   // stage(t) drained
    } else {
      asm volatile("s_waitcnt vmcnt(0)" ::: "memory");
    }
    __builtin_amdgcn_s_barrier();            // slot s fully staged (all waves)
    __builtin_amdgcn_sched_barrier(0);
    const int bA = s * 32768, bB = s * 32768 + 16384;
    #pragma unroll
    for (int kk = 0; kk < 2; kk++) {
      short8 bv[4];
      #pragma unroll
      for (int ci = 0; ci < 4; ci++)
        bv[ci] = *(const short8*)&smem[bB + (wc * 64 + ci * 16 + lr) * 64 +
                                       (((kk << 2) + q) ^ sx) * 8];
      #pragma unroll
      for (int ri = 0; ri < 8; ri++) {
        short8 av = *(const short8*)&smem[bA + (wr * 128 + ri * 16 + lr) * 64 +
                                          (((kk << 2) + q) ^ sx) * 8];
        #pragma unroll
        for (int ci = 0; ci < 4; ci++)
          acc[ri][ci] = __builtin_amdgcn_mfma_f32_16x16x32_bf16(
              av, bv[ci], acc[ri][ci], 0, 0, 0);
      }
    }
  }
  __syncthreads();   // full drain; LDS free for epilogue staging

  const int dr = (lane >> 4) * 4;
  float invc[4];
  if (HAS_CSP) {
    #pragma unroll
    for (int ci = 0; ci < 4; ci++) invc[ci] = invs[wc * 64 + ci * 16 + lr];
  }
  float rowsum[8][4], rowsq[8][4];
  if (HAS_EXP || HAS_PSUM2) {
    #pragma unroll
    for (int ri = 0; ri < 8; ri++)
      #pragma unroll
      for (int r = 0; r < 4; r++) { rowsum[ri][r] = 0.f; rowsq[ri][r] = 0.f; }
  }
  #pragma unroll
  for (int ri = 0; ri < 8; ri++) {
    const int rowl = wr * 128 + ri * 16 + dr;
    const int rowb = bm + rowl;
    float bvs[4] = {0.f, 0.f, 0.f, 0.f};
    float shv[4] = {0.f, 0.f, 0.f, 0.f};
    if (HAS_BIAS) {
      #pragma unroll
      for (int r = 0; r < 4; r++) bvs[r] = bias[rowb + r];
    }
    if (HAS_SHIFT) {
      #pragma unroll
      for (int r = 0; r < 4; r++) shv[r] = shift[rowb + r];
    }
    #pragma unroll
    for (int ci = 0; ci < 4; ci++) {
      const int coll = wc * 64 + ci * 16 + lr;
      float v[4];
      #pragma unroll
      for (int r = 0; r < 4; r++) {
        float tv = acc[ri][ci][r] * scale;
        if (HAS_CSP) tv *= invc[ci];
        if (HAS_SHIFT) tv -= shv[r];
        if (HAS_BIAS) tv += bvs[r];
        if (HAS_EXP) tv = expf(tv);
        if (HAS_EXP || HAS_PSUM2) rowsum[ri][r] += tv;
        if (HAS_PSUM2) rowsq[ri][r] += tv * tv;
        v[r] = tv;
      }
      if (OM == 1) {
        u16x4 w;
        #pragma unroll
        for (int r = 0; r < 4; r++) w[r] = f2bf(v[r]);
        unsigned bo = (unsigned)((coll * 256 + rowl) * 2) ^ ((coll & 7) << 4);
        *(u16x4*)((char*)smem + bo) = w;
      } else {
        #pragma unroll
        for (int r = 0; r < 4; r++) smem[(rowl + r) * 256 + coll] = f2bf(v[r]);
      }
    }
  }
  if (HAS_EXP || HAS_PSUM2) {
    #pragma unroll
    for (int msk = 1; msk < 16; msk <<= 1)
      #pragma unroll
      for (int ri = 0; ri < 8; ri++)
        #pragma unroll
        for (int r = 0; r < 4; r++) {
          rowsum[ri][r] += __shfl_xor(rowsum[ri][r], msk);
          if (HAS_PSUM2) rowsq[ri][r] += __shfl_xor(rowsq[ri][r], msk);
        }
    if ((lane & 15) == 0) {
      #pragma unroll
      for (int ri = 0; ri < 8; ri++)
        #pragma unroll
        for (int r = 0; r < 4; r++) {
          psum[wc][wr * 128 + ri * 16 + dr + r] = rowsum[ri][r];
          if (HAS_PSUM2) psumq[wc][wr * 128 + ri * 16 + dr + r] = rowsq[ri][r];
        }
    }
  }
  __syncthreads();
  u16* C = (u16*)Cv + blockIdx.z * sC;
  if (OM == 1) {
    #pragma unroll
    for (int i = 0; i < 16; i++) {
      const int chunk = i * 512 + tid;
      const int coll = chunk >> 5, rq = chunk & 31;
      unsigned bo = (unsigned)(coll * 512 + rq * 16) ^ ((coll & 7) << 4);
      uint4 w = *(const uint4*)((const char*)smem + bo);
      *(uint4*)(C + (long)(bn + coll) * M + bm + rq * 8) = w;
    }
  } else {
    #pragma unroll
    for (int i = 0; i < 16; i++) {
      const int chunk = i * 512 + tid;
      const int row = chunk >> 5, cq = chunk & 31;
      uint4 w = *(const uint4*)(smem + row * 256 + cq * 8);
      *(uint4*)(C + (long)(bm + row) * N + bn + cq * 8) = w;
    }
  }
  if ((HAS_EXP || HAS_PSUM2) && tid < 256) {
    if (HAS_EXP)
      psum_out[((long)blockIdx.z * gridDim.x + blockIdx.x) * 4096 + bm + tid] =
          psum[0][tid] + psum[1][tid] + psum[2][tid] + psum[3][tid];
    if (HAS_PSUM2) {
      const long blk = ((long)blockIdx.z * gridDim.y + blockIdx.y) * gridDim.x
                       + blockIdx.x;
      psum_out[blk * 512 + tid] =
          psum[0][tid] + psum[1][tid] + psum[2][tid] + psum[3][tid];
      psum_out[blk * 512 + 256 + tid] =
          psumq[0][tid] + psumq[1][tid] + psumq[2][tid] + psumq[3][tid];
    }
  }
}

// ---------------- old 128x128 GEMM (kept for merged phi+g) ----------------
template<int OM, bool HAS_BIAS, bool HAS_CS, bool HAS_SHIFT, bool HAS_EXP,
         bool HAS_PSUM2, bool HAS_CSP>
__global__ __launch_bounds__(256)
void gemm_tn(const u16* __restrict__ A, const u16* __restrict__ B,
             void* __restrict__ Cv, void* __restrict__ Cv2,
             const float* __restrict__ bias, const float* __restrict__ bias2,
             long sBias,
             const float* __restrict__ cs, long sCS,
             const float* __restrict__ shift, long sShift,
             float* __restrict__ psum_out,
             float scale, int M, int N, int K, long sA, long sB, long sC)
{
  A += blockIdx.z * sA;
  B += blockIdx.z * sB;
  if (HAS_BIAS) bias += blockIdx.z * sBias;
  if (HAS_CS || HAS_CSP) cs += blockIdx.z * sCS;
  if (HAS_SHIFT) shift += blockIdx.z * sShift;
  const int bm = blockIdx.y * 128;
  const int bn = blockIdx.x * 128;
  __shared__ __align__(16) u16 smem[128 * 128];
  u16* As = smem;
  u16* Bs = smem + 128 * 64;
  __shared__ float psum[4][128];
  const int tid = threadIdx.x;
  const int lane = tid & 63;
  const int wave = tid >> 6;
  const int wm = (wave >> 1) * 64;
  const int wn = (wave & 1) * 64;
  const int lr = lane & 15;
  const int q  = lane >> 4;
  const int sxor = lane & 7;
  const bool gps = (OM == 3) && (bm >= 512);
  f32x4 acc[4][4] = {};

  if (HAS_CSP) {
    if (tid < 128) {
      float s = 0.f;
      #pragma unroll
      for (int xx = 0; xx < 8; xx++) s += cs[xx * 4096 + bn + tid];
      psum[0][tid] = 1.0f / s;
    }
  }

  const int swz = ((lane & 7) ^ (lane >> 3)) * 8;
  const long grow = 32 * wave + (lane >> 3);
  const u16* Ag = A + ((long)bm + grow) * K + swz;
  const u16* Bg = B + ((long)bn + grow) * K + swz;

  for (int kt = 0; kt < K; kt += 64) {
    __syncthreads();
    #pragma unroll
    for (int i = 0; i < 4; i++) {
      gload16(Ag + (long)(8 * i) * K + kt, &As[(wave * 4 + i) * 512]);
      gload16(Bg + (long)(8 * i) * K + kt, &Bs[(wave * 4 + i) * 512]);
    }
    __syncthreads();
    #pragma unroll
    for (int kk = 0; kk < 2; kk++) {
      short8 av[4], bv[4];
      #pragma unroll
      for (int mi = 0; mi < 4; mi++)
        av[mi] = *(const short8*)&As[(wm + mi * 16 + lr) * 64 +
                                     (((kk << 2) + q) ^ sxor) * 8];
      #pragma unroll
      for (int ni = 0; ni < 4; ni++)
        bv[ni] = *(const short8*)&Bs[(wn + ni * 16 + lr) * 64 +
                                     (((kk << 2) + q) ^ sxor) * 8];
      #pragma unroll
      for (int mi = 0; mi < 4; mi++) {
        #pragma unroll
        for (int ni = 0; ni < 4; ni++)
          acc[mi][ni] = __builtin_amdgcn_mfma_f32_16x16x32_bf16(
              av[mi], bv[ni], acc[mi][ni], 0, 0, 0);
      }
    }
  }

  float invc[4];
  if (HAS_CSP) {
    #pragma unroll
    for (int ni = 0; ni < 4; ni++) invc[ni] = psum[0][wn + ni * 16 + lr];
  }
  __syncthreads();
  const int dr = (lane >> 4) * 4;
  const bool trans_out = (OM == 1) || (OM == 3 && !gps);
  float rowsum[4][4];
  float rowsq[4][4];
  if (HAS_EXP || HAS_PSUM2 || gps) {
    #pragma unroll
    for (int mi = 0; mi < 4; mi++)
      #pragma unroll
      for (int r = 0; r < 4; r++) { rowsum[mi][r] = 0.f; rowsq[mi][r] = 0.f; }
  }
  const float* bp = (OM == 3 && gps) ? bias2 - 512 : bias;
  #pragma unroll
  for (int mi = 0; mi < 4; mi++) {
    const int rowl = wm + mi * 16 + dr;
    const int rowb = bm + rowl;
    float bvs[4] = {0.f, 0.f, 0.f, 0.f};
    float shv[4] = {0.f, 0.f, 0.f, 0.f};
    if (HAS_BIAS) {
      #pragma unroll
      for (int r = 0; r < 4; r++) bvs[r] = bp[rowb + r];
    }
    if (HAS_SHIFT) {
      #pragma unroll
      for (int r = 0; r < 4; r++) shv[r] = shift[rowb + r];
    }
    #pragma unroll
    for (int ni = 0; ni < 4; ni++) {
      const int coll = wn + ni * 16 + lr;
      const float csv = HAS_CSP ? invc[ni] : (HAS_CS ? cs[bn + coll] : 1.0f);
      float v[4];
      #pragma unroll
      for (int r = 0; r < 4; r++) {
        float t = acc[mi][ni][r] * scale;
        if (HAS_CS || HAS_CSP) t *= csv;
        if (HAS_SHIFT) t -= shv[r];
        if (HAS_BIAS) t += bvs[r];
        if (HAS_EXP) t = expf(t);
        if (HAS_EXP || HAS_PSUM2 || gps) rowsum[mi][r] += t;
        if (HAS_PSUM2) rowsq[mi][r] += t * t;
        v[r] = t;
      }
      if (trans_out) {
        u16x4 w;
        #pragma unroll
        for (int r = 0; r < 4; r++) w[r] = f2bf(v[r]);
        unsigned bo = (unsigned)((coll * 128 + rowl) * 2) ^ ((coll & 7) << 4);
        *(u16x4*)((char*)smem + bo) = w;
      } else {
        #pragma unroll
        for (int r = 0; r < 4; r++) smem[(rowl + r) * 128 + coll] = f2bf(v[r]);
      }
    }
  }
  if (HAS_EXP || HAS_PSUM2 || gps) {
    #pragma unroll
    for (int msk = 1; msk < 16; msk <<= 1)
      #pragma unroll
      for (int mi = 0; mi < 4; mi++)
        #pragma unroll
        for (int r = 0; r < 4; r++) {
          rowsum[mi][r] += __shfl_xor(rowsum[mi][r], msk);
          if (HAS_PSUM2) rowsq[mi][r] += __shfl_xor(rowsq[mi][r], msk);
        }
    if ((lane & 15) == 0) {
      #pragma unroll
      for (int mi = 0; mi < 4; mi++)
        #pragma unroll
        for (int r = 0; r < 4; r++) {
          psum[wave & 1][wm + mi * 16 + dr + r] = rowsum[mi][r];
          if (HAS_PSUM2) psum[2 + (wave & 1)][wm + mi * 16 + dr + r] = rowsq[mi][r];
        }
    }
  }
  __syncthreads();
  if (trans_out) {
    const int Ms = (OM == 3) ? 512 : M;
    u16* C = (u16*)Cv + blockIdx.z * sC;
    #pragma unroll
    for (int i = 0; i < 8; i++) {
      const int chunk = i * 256 + tid;
      const int coll = chunk >> 4, rq = chunk & 15;
      unsigned bo = (unsigned)(coll * 256 + rq * 16) ^ ((coll & 7) << 4);
      uint4 w = *(const uint4*)((const char*)smem + bo);
      *(uint4*)(C + (long)(bn + coll) * Ms + bm + rq * 8) = w;
    }
  } else {
    u16* C = (OM == 3) ? (u16*)Cv2 + blockIdx.z * sC : (u16*)Cv + blockIdx.z * sC;
    const int rbase = (OM == 3) ? bm - 512 : bm;
    #pragma unroll
    for (int i = 0; i < 8; i++) {
      const int chunk = i * 256 + tid;
      const int row = chunk >> 4, cq = chunk & 15;
      uint4 w = *(const uint4*)(smem + row * 128 + cq * 8);
      *(uint4*)(C + (long)(rbase + row) * N + bn + cq * 8) = w;
    }
  }
  if (HAS_EXP || HAS_PSUM2 || gps) {
    if (tid < 128) {
      if (HAS_EXP)
        psum_out[((long)blockIdx.z * gridDim.x + blockIdx.x) * 4096 + bm + tid] =
            psum[0][tid] + psum[1][tid];
      if (HAS_PSUM2) {
        const long blk = ((long)blockIdx.z * gridDim.y + blockIdx.y) * gridDim.x
                         + blockIdx.x;
        psum_out[blk * 256 + tid] = psum[0][tid] + psum[1][tid];
        psum_out[blk * 256 + 128 + tid] = psum[2][tid] + psum[3][tid];
      }
      if (gps)
        psum_out[((long)blockIdx.z * gridDim.x + blockIdx.x) * 512 +
                 (bm - 512) + tid] = psum[0][tid] + psum[1][tid];
    }
  }
}

// ------- gbar[b][d] = (1/1024) * sum_x g_ps[b][x][d] --------------------
__global__ __launch_bounds__(256) void gbar_kernel(const float* __restrict__ g_ps,
                                                   float* __restrict__ gbar) {
  const int idx = blockIdx.x * 256 + threadIdx.x;   // 0..4095 = b*512+d
  const int b = idx >> 9, d = idx & 511;
  const float* p = g_ps + (long)b * 8 * 512 + d;
  float s = 0.f;
  #pragma unroll
  for (int xx = 0; xx < 8; xx++) s += p[(long)xx * 512];
  gbar[idx] = s * (1.0f / 1024.0f);
}

// ------- c0[b][c] = out_b[c] + sum_d out_w_f32[c][d]*gbar[b][d] ----------
__global__ __launch_bounds__(256) void c0_kernel(const float* __restrict__ out_w,
                                                 const float* __restrict__ out_b,
                                                 const float* __restrict__ gbar,
                                                 float* __restrict__ c0) {
  const int idx = blockIdx.x * 4 + (threadIdx.x >> 6);   // 0..8191 = b*1024+c
  const int lane = threadIdx.x & 63;
  const int b = idx >> 10, c = idx & 1023;
  const int d0 = lane * 8;
  float4 w0 = *(const float4*)(out_w + (long)c * DI + d0);
  float4 w1 = *(const float4*)(out_w + (long)c * DI + d0 + 4);
  float4 g0 = *(const float4*)(gbar + (long)b * DI + d0);
  float4 g1 = *(const float4*)(gbar + (long)b * DI + d0 + 4);
  float s = w0.x * g0.x + w0.y * g0.y + w0.z * g0.z + w0.w * g0.w
          + w1.x * g1.x + w1.y * g1.y + w1.z * g1.z + w1.w * g1.w;
  #pragma unroll
  for (int off = 32; off > 0; off >>= 1) s += __shfl_xor(s, off);
  if (lane == 0) c0[idx] = out_b[c] + s;
}

// ------ BN stats from y-GEMM (256-tile) partials + c0 --------------------
// partial blk = (b*4 + by)*16 + bx ; [0..255]=sum, [256..511]=sq
__global__ __launch_bounds__(256) void stats2_kernel(const float* __restrict__ partial,
                                                     const float* __restrict__ c0,
                                                     float* __restrict__ stats) {
  const int co = blockIdx.x * 256 + threadIdx.x;  // 0..1023
  const int by = co >> 8, r = co & 255;
  float sd = 0.f, sd2 = 0.f, sbc = 0.f;
  for (int b = 0; b < 8; b++) {
    float sb = 0.f, qb = 0.f;
    #pragma unroll
    for (int bx = 0; bx < 16; bx++) {
      const long blk = (((long)b * 4 + by) * 16 + bx) * 512;
      sb += partial[blk + r];
      qb += partial[blk + 256 + r];
    }
    sd += sb; sd2 += qb;
    sbc += c0[b * 1024 + co] * sb;
  }
  float sc0 = 0.f, sc02 = 0.f;
  #pragma unroll
  for (int b = 0; b < 8; b++) {
    float c = c0[b * 1024 + co];
    sc0 += c; sc02 += c * c;
  }
  stats[co] = 4096.0f * sc0 + sd;
  stats[1024 + co] = 4096.0f * sc02 + 2.0f * sbc + sd2;
}

// ---------------- BN apply + residual (bf16 dy + c0) ----------------
__global__ __launch_bounds__(256) void final_kernel(const u16* __restrict__ dy,
    const float* __restrict__ x, const float* __restrict__ stats,
    const float* __restrict__ c0,
    const float* __restrict__ bnw, const float* __restrict__ bnb,
    float* __restrict__ out) {
  const int bc = blockIdx.x;
  const int co = bc & 1023;
  const float mean = stats[co] * (1.0f / 32768.0f);
  const float var = stats[1024 + co] * (1.0f / 32768.0f) - mean * mean;
  const float inv = rsqrtf(var + 1e-5f) * bnw[co];
  const float addc = bnb[co] - mean * inv + c0[bc] * inv;
  const long base = (long)bc * 4096;
  const int t = threadIdx.x;
  #pragma unroll
  for (int i = 0; i < 2; i++) {
    const long off = base + (long)(i * 256 + t) * 8;
    uint4 v = *(const uint4*)(dy + off);
    float f[8]; unpack8(v, f);
    const float4 x0 = *(const float4*)(x + off);
    const float4 x1 = *(const float4*)(x + off + 4);
    float4 o0, o1;
    o0.x = f[0] * inv + addc + x0.x;
    o0.y = f[1] * inv + addc + x0.y;
    o0.z = f[2] * inv + addc + x0.z;
    o0.w = f[3] * inv + addc + x0.w;
    o1.x = f[4] * inv + addc + x1.x;
    o1.y = f[5] * inv + addc + x1.y;
    o1.z = f[6] * inv + addc + x1.z;
    o1.w = f[7] * inv + addc + x1.w;
    *(float4*)(out + off) = o0;
    *(float4*)(out + off + 4) = o1;
  }
}

extern "C" void kernel_launch(void* const* d_in, const int* in_sizes, int n_in,
                              void* d_out, int out_size, void* d_ws, size_t ws_size,
                              hipStream_t stream) {
  (void)in_sizes; (void)n_in; (void)out_size; (void)ws_size;
  const float* x       = (const float*)d_in[0];
  const float* theta_w = (const float*)d_in[1];
  const float* theta_b = (const float*)d_in[2];
  const float* phi_w   = (const float*)d_in[3];
  const float* phi_b   = (const float*)d_in[4];
  const float* g_w     = (const float*)d_in[5];
  const float* g_b     = (const float*)d_in[6];
  const float* out_w   = (const float*)d_in[7];
  const float* out_b   = (const float*)d_in[8];
  const float* bn_w    = (const float*)d_in[9];
  const float* bn_b    = (const float*)d_in[10];
  float* out = (float*)d_out;
  char* ws = (char*)d_ws;
  const size_t MB = 1024 * 1024;

  // workspace layout
  u16* xT     = (u16*)(ws + 0 * MB);       // 64MB; later: dy bf16 [0,64MB)
  u16* poolT  = (u16*)(ws + 64 * MB);      // 16MB
  u16* w_th   = (u16*)(ws + 80 * MB);      // 1MB
  u16* w_ph   = (u16*)(ws + 81 * MB);      // 1MB  (w_ph || w_g contiguous)
  u16* w_g    = (u16*)(ws + 82 * MB);      // 1MB
  u16* thetaT = (u16*)(ws + 84 * MB);      // 32MB
  u16* phiT   = (u16*)(ws + 116 * MB);     // 8MB
  u16* g_n    = (u16*)(ws + 124 * MB);     // 8MB
  u16* e      = (u16*)(ws + 132 * MB);     // 64MB (exp(scores))
  u16* tT     = (u16*)(ws + 196 * MB);     // 32MB (delta-t bf16)
  u16* w_out  = (u16*)(ws + 228 * MB);     // 1MB
  float* gbar  = (float*)(ws + 229 * MB);            // 16KB
  float* c0b   = (float*)(ws + 229 * MB + 16384);    // 32KB
  float* stats = (float*)(ws + 229 * MB + 49152);    // 8KB
  float* partial = (float*)(ws + 230 * MB);          // 512KB (8*4*4096 f32)
  float* partial2 = (float*)(ws + 231 * MB);         // 1MB (512 blk * 512 f32)
  float* g_ps = (float*)(ws + 233 * MB);             // 128KB (8*8*512 f32)
  u16* dy = xT;               // alias: x_T dead after theta GEMM

  // 1. weights -> bf16 (single launch)
  cvt4_kernel<<<2048, 256, 0, stream>>>(theta_w, phi_w, g_w, out_w,
                                        w_th, w_ph, w_g, w_out);
  // 2. x -> x_T bf16 with fused 2x2 maxpool
  transpose_pool_kernel<<<dim3(32, 16, 8), 256, 0, stream>>>(x, xT, poolT);
  // 4. theta -> theta_T [b][4096][512]  (256-tile dbuf GEMM)
  gemm256<1, true, false, false, false, false>
      <<<dim3(16, 2, 8), 512, 0, stream>>>(
      w_th, xT, thetaT, theta_b, 0L, nullptr, 0L, nullptr, 0L, nullptr,
      1.0f, 512, 4096, 1024, 0L, (long)NPIX * CIN, (long)NPIX * DI);
  // 5+6. merged phi+g GEMM (128-tile kernel)
  gemm_tn<3, true, false, false, false, false, false>
      <<<dim3(8, 8, 8), 256, 0, stream>>>(
      w_ph, poolT, phiT, g_n, phi_b, g_b, 0L, nullptr, 0L, nullptr, 0L,
      g_ps, 1.0f, 1024, 1024, 1024, 0L, (long)MPIX * CIN, (long)MPIX * DI);
  // 6b. gbar from partials ; c0
  gbar_kernel<<<16, 256, 0, stream>>>(g_ps, gbar);
  c0_kernel<<<2048, 256, 0, stream>>>(out_w, out_b, gbar, c0b);
  // 7. e[n][m] = exp(scores) + per-block rowsum partials (gridX=4)
  gemm256<0, false, false, true, false, false>
      <<<dim3(4, 16, 8), 512, 0, stream>>>(
      thetaT, phiT, e, nullptr, 0L, nullptr, 0L, nullptr, 0L, partial,
      0.044194173824159216f, 4096, 1024, 512,
      (long)NPIX * DI, (long)MPIX * DI, (long)NPIX * MPIX);
  // 8+9. delta-t = (g_n * e^T)*inv[n] - gbar[d]; inv from partials (CSP)
  gemm256<1, false, true, false, false, true>
      <<<dim3(16, 2, 8), 512, 0, stream>>>(
      g_n, e, tT, nullptr, 0L, partial, 16384L, gbar, 512L, nullptr,
      1.0f, 512, 4096, 1024,
      (long)DI * MPIX, (long)NPIX * MPIX, (long)NPIX * DI);
  // 10. dy = out_w * delta-t^T + BN partials (PSUM2)
  gemm256<0, false, false, false, true, false>
      <<<dim3(16, 4, 8), 512, 0, stream>>>(
      w_out, tT, dy, nullptr, 0L, nullptr, 0L, nullptr, 0L, partial2,
      1.0f, 1024, 4096, 512, 0L, (long)NPIX * DI, (long)1024 * NPIX);
  // 11. BN stats from partials + c0 (deterministic)
  stats2_kernel<<<4, 256, 0, stream>>>(partial2, c0b, stats);
  // 12. BN apply + residual
  final_kernel<<<8192, 256, 0, stream>>>(dy, x, stats, c0b, bn_w, bn_b, out);
}